// Round 6
// baseline (642.403 us; speedup 1.0000x reference)
//
#include <hip/hip_runtime.h>
#include <cmath>

typedef unsigned short u16;
typedef __attribute__((ext_vector_type(8))) __bf16 bf16x8;
typedef __attribute__((ext_vector_type(4))) float f32x4;

constexpr int Bb = 2, Tt = 8, Dc = 128, PIX = 4096; // b=2, c=128, 64x64 imgs

__device__ inline u16 f2bf(float f) {
    unsigned u = __builtin_bit_cast(unsigned, f);
    u += 0x7fffu + ((u >> 16) & 1u);
    return (u16)(u >> 16);
}
__device__ inline float bf2f(u16 h) {
    unsigned u = ((unsigned)h) << 16;
    return __builtin_bit_cast(float, u);
}

// ---------------------------------------------------------------------------
// Register-direct bf16 NT MFMA core with 4-SLOT rolling pipeline.
// C(128x128) = A(128xK)*B(128xK)^T. Preloads chunks 0..3; computing slot s
// then refilling it with chunk t+4 keeps ~3 chunks (~230+ cyc) of loads in
// flight -- matched to L2 latency (round-5's 1-chunk lookahead = 78 cyc was
// the measured 8.8% MfmaUtil failure). kChunks must be a multiple of 4.
// ---------------------------------------------------------------------------
__device__ inline void mfma_nt_pipe(const u16* __restrict__ A, int ldkA,
                                    const u16* __restrict__ B, int ldkB,
                                    int kChunks, int wave, int lane,
                                    f32x4 (&acc)[4][4])
{
    const int wm = (wave >> 1) * 64, wn = (wave & 1) * 64;
    const int fr = lane & 15;
    const int kq = (lane >> 4) * 8;
    const u16* Ap = A + (size_t)(wm + fr) * ldkA + kq;
    const u16* Bp = B + (size_t)(wn + fr) * ldkB + kq;
    bf16x8 aq[4][4], bq[4][4];
#pragma unroll
    for (int s = 0; s < 4; ++s)
#pragma unroll
        for (int i = 0; i < 4; ++i) {
            aq[s][i] = *(const bf16x8*)(Ap + (size_t)(i * 16) * ldkA + s * 32);
            bq[s][i] = *(const bf16x8*)(Bp + (size_t)(i * 16) * ldkB + s * 32);
        }
    for (int kb = 0; kb < kChunks; kb += 4) {
#pragma unroll
        for (int s = 0; s < 4; ++s) {
#pragma unroll
            for (int i = 0; i < 4; ++i)
#pragma unroll
                for (int j = 0; j < 4; ++j)
                    acc[i][j] = __builtin_amdgcn_mfma_f32_16x16x32_bf16(aq[s][i], bq[s][j], acc[i][j], 0, 0, 0);
            const int t = kb + s + 4;
            if (t < kChunks) {
#pragma unroll
                for (int i = 0; i < 4; ++i) {
                    aq[s][i] = *(const bf16x8*)(Ap + (size_t)(i * 16) * ldkA + t * 32);
                    bq[s][i] = *(const bf16x8*)(Bp + (size_t)(i * 16) * ldkB + t * 32);
                }
            }
        }
    }
}

// ---------------------------------------------------------------------------
// Weight prep: Wqkv[3*128][128] bf16 stacked; WoT[tap][cout][cin] bf16.
// ---------------------------------------------------------------------------
__global__ void k_prep(const float* __restrict__ wq, const float* __restrict__ wk,
                       const float* __restrict__ wv, const float* __restrict__ wo,
                       u16* __restrict__ Wqkv, u16* __restrict__ WoT)
{
    int idx = blockIdx.x * 256 + threadIdx.x;
    if (idx < 49152) {
        const float* w = idx < 16384 ? wq : (idx < 32768 ? wk : wv);
        Wqkv[idx] = f2bf(w[idx & 16383]);
    }
    int j = idx - 49152;
    if (j >= 0 && j < 147456) {
        int tap = j / 16384, rem = j % 16384;  // rem = cout*128+cin
        WoT[j] = f2bf(wo[(size_t)rem * 9 + tap]);
    }
}

// ---------------------------------------------------------------------------
// Xt[n][pix][cin] bf16 from x[n][cin][pix] fp32 (LDS transpose, 64-pix tiles)
// ---------------------------------------------------------------------------
__global__ __launch_bounds__(256) void k_xt(const float* __restrict__ x, u16* __restrict__ Xt)
{
    __shared__ float ls[128 * 65];
    const int n = blockIdx.y, pix0 = blockIdx.x * 64;
#pragma unroll
    for (int rep = 0; rep < 32; ++rep) {
        int idx = rep * 256 + threadIdx.x;
        int cin = idx >> 6, p = idx & 63;
        ls[cin * 65 + p] = x[((size_t)n * Dc + cin) * PIX + pix0 + p];
    }
    __syncthreads();
#pragma unroll
    for (int rep = 0; rep < 32; ++rep) {
        int idx = rep * 256 + threadIdx.x;
        int p = idx >> 7, cin = idx & 127;
        Xt[((size_t)n * PIX + pix0 + p) * Dc + cin] = f2bf(ls[cin * 65 + p]);
    }
}

// ---------------------------------------------------------------------------
// Fused QKV: C[384][4096] = Wqkv * Xt^T per image; bf16 out + bias, routed.
// grid (32 pixtiles, 3 Mtiles, 16 imgs)
// ---------------------------------------------------------------------------
__global__ __launch_bounds__(256) void k_qkv_mfma(const u16* __restrict__ Wqkv,
                                                  const u16* __restrict__ Xt,
                                                  const float* __restrict__ bq,
                                                  const float* __restrict__ bk,
                                                  const float* __restrict__ bv,
                                                  u16* __restrict__ q_bf,
                                                  u16* __restrict__ k_bf,
                                                  u16* __restrict__ v_bf)
{
    const int tid = threadIdx.x, wave = tid >> 6, lane = tid & 63;
    const int mt = blockIdx.y, n = blockIdx.z, px0 = blockIdx.x * 128;
    f32x4 acc[4][4];
#pragma unroll
    for (int i = 0; i < 4; ++i)
#pragma unroll
        for (int j = 0; j < 4; ++j) acc[i][j] = (f32x4){0.f, 0.f, 0.f, 0.f};
    mfma_nt_pipe(Wqkv + (size_t)mt * 128 * 128, 128,
                 Xt + ((size_t)n * PIX + px0) * 128, 128, 4, wave, lane, acc);
    const int wm = (wave >> 1) * 64, wn = (wave & 1) * 64;
    const int rb = (lane >> 4) * 4, cb = lane & 15;
#pragma unroll
    for (int i = 0; i < 4; ++i)
#pragma unroll
        for (int reg = 0; reg < 4; ++reg) {
            int gmg = mt * 128 + wm + i * 16 + rb + reg;     // stacked cout 0..383
            int sel = gmg >> 7, c = gmg & 127;
            float bias = (sel == 0 ? bq : sel == 1 ? bk : bv)[c];
            u16* dst = (sel == 0 ? q_bf : sel == 1 ? k_bf : v_bf);
#pragma unroll
            for (int j = 0; j < 4; ++j) {
                int pix = px0 + wn + j * 16 + cb;
                dst[((size_t)n * Dc + c) * PIX + pix] = f2bf(acc[i][j][reg] + bias);
            }
        }
}

// ---------------------------------------------------------------------------
// depthwise 3x3 add into bf16 v_all. grid (16, 128, 16)
// ---------------------------------------------------------------------------
__global__ __launch_bounds__(256) void k_vdw(const float* __restrict__ X,
                                             const float* __restrict__ wvle,
                                             const float* __restrict__ bvle,
                                             u16* __restrict__ v_bf)
{
    const int n = blockIdx.z, c = blockIdx.y;
    const int p = blockIdx.x * 256 + threadIdx.x;
    const int y = p >> 6, x = p & 63;
    const float* xp = X + ((size_t)n * Dc + c) * PIX;
    const float* w  = wvle + c * 9;
    float s = bvle[c];
#pragma unroll
    for (int ky = 0; ky < 3; ++ky) {
        int yy = y + ky - 1;
        if (yy < 0 || yy >= 64) continue;
#pragma unroll
        for (int kx = 0; kx < 3; ++kx) {
            int xx = x + kx - 1;
            if (xx < 0 || xx >= 64) continue;
            s += w[ky * 3 + kx] * xp[yy * 64 + xx];
        }
    }
    size_t idx = ((size_t)n * Dc + c) * PIX + p;
    v_bf[idx] = f2bf(bf2f(v_bf[idx]) + s);
}

// ---------------------------------------------------------------------------
// Depth path, kernel 1: d1[n][c][128][128] = relu(conv(dm, wd1, s2, p1)) bf16.
// ---------------------------------------------------------------------------
__global__ __launch_bounds__(256) void k_d1(const float* __restrict__ dm,
                                            const float* __restrict__ wd1,
                                            const float* __restrict__ bd1,
                                            u16* __restrict__ d1b)
{
    __shared__ float ls[17 * 132];
    const int n = blockIdx.y;
    const int yt = blockIdx.x >> 1, xh = blockIdx.x & 1;
    const int Y0 = yt * 8;
    const int tid = threadIdx.x;
    const float* dmp = dm + (size_t)n * 65536;
    for (int idx = tid; idx < 17 * 132; idx += 256) {
        int row = idx / 132, cl = idx % 132;
        int gr = 2 * Y0 - 1 + row;
        int gc = 128 * xh - 1 + cl;
        float v = 0.f;
        if (gr >= 0 && gr < 256 && gc >= 0 && gc < 256 && cl < 129) v = dmp[gr * 256 + gc];
        ls[idx] = v;
    }
    __syncthreads();
    const int Xl = tid & 63;
    const int Yl0 = tid >> 6;                 // rows Yl0 and Yl0+4
    float in0[9], in1[9];
#pragma unroll
    for (int jy = 0; jy < 3; ++jy)
#pragma unroll
        for (int jx = 0; jx < 3; ++jx) {
            in0[jy * 3 + jx] = ls[(2 * Yl0 + jy) * 132 + 2 * Xl + jx];
            in1[jy * 3 + jx] = ls[(2 * (Yl0 + 4) + jy) * 132 + 2 * Xl + jx];
        }
    const int X = 64 * xh + Xl;
    u16* outbase = d1b + (size_t)n * Dc * 16384 + (size_t)Y0 * 128 + X;
    for (int c = 0; c < 128; ++c) {
        const float* w1 = wd1 + c * 9;        // uniform -> s_load
        float a0 = bd1[c], a1 = a0;
#pragma unroll
        for (int t = 0; t < 9; ++t) { a0 += w1[t] * in0[t]; a1 += w1[t] * in1[t]; }
        u16* ob = outbase + (size_t)c * 16384;
        ob[(size_t)Yl0 * 128]       = f2bf(fmaxf(a0, 0.f));
        ob[(size_t)(Yl0 + 4) * 128] = f2bf(fmaxf(a1, 0.f));
    }
}

// ---------------------------------------------------------------------------
// Depth path, kernel 2: partial conv2 over 16-channel groups.
// ---------------------------------------------------------------------------
__global__ __launch_bounds__(256) void k_d2p(const u16* __restrict__ d1b,
                                             const float* __restrict__ wd2,
                                             float* __restrict__ part)
{
    __shared__ u16 ls[33 * 136];              // payload at cl 8..135, zero at cl 7
    const int yt = blockIdx.x, n = blockIdx.y, cg = blockIdx.z;
    const int tid = threadIdx.x;
    const int y0 = yt * 16;
    if (tid < 33) ls[tid * 136 + 7] = 0;
    const int x = tid & 63;
    const int yl0 = (tid >> 6) * 4;
    float acc[4] = {0.f, 0.f, 0.f, 0.f};
    for (int c = 0; c < 16; ++c) {
        const u16* src = d1b + ((size_t)n * Dc + cg * 16 + c) * 16384;
        __syncthreads();
        for (int idx = tid; idx < 33 * 16; idx += 256) {
            int row = idx >> 4, s = idx & 15;
            int gr = 2 * y0 - 1 + row;
            uint4 v = make_uint4(0, 0, 0, 0);
            if (gr >= 0 && gr < 128) v = *(const uint4*)(src + gr * 128 + s * 8);
            *(uint4*)&ls[row * 136 + 8 + s * 8] = v;
        }
        __syncthreads();
        const float* w2 = wd2 + (cg * 16 + c) * 9;   // uniform -> s_load
        float w[9];
#pragma unroll
        for (int t = 0; t < 9; ++t) w[t] = w2[t];
#pragma unroll
        for (int r = 0; r < 4; ++r) {
            int yl = yl0 + r;
#pragma unroll
            for (int ky = 0; ky < 3; ++ky) {
                const u16* rp = &ls[(2 * yl + ky) * 136 + 2 * x + 7];
                float v0 = bf2f(rp[0]);
                unsigned pr = *(const unsigned*)(rp + 1);
                float v1 = bf2f((u16)(pr & 0xffffu));
                float v2 = bf2f((u16)(pr >> 16));
                acc[r] += w[ky * 3 + 0] * v0 + w[ky * 3 + 1] * v1 + w[ky * 3 + 2] * v2;
            }
        }
    }
    float* pp = part + ((size_t)cg * 16 + n) * PIX;
#pragma unroll
    for (int r = 0; r < 4; ++r)
        pp[(y0 + yl0 + r) * 64 + x] = acc[r];
}

// Depth path, kernel 3: dep = relu(sum_cg part + bd2). grid (256)
__global__ void k_dfin(const float* __restrict__ part, const float* __restrict__ bd2,
                       float* __restrict__ dep)
{
    int idx = blockIdx.x * 256 + threadIdx.x;
    float s = bd2[0];
#pragma unroll
    for (int cg = 0; cg < 8; ++cg) s += part[(size_t)cg * 65536 + idx];
    dep[idx] = fmaxf(s, 0.f);
}

// ---------------------------------------------------------------------------
// Wave-parallel per-token stats (min/max/mask butterfly, exact median rank).
// ---------------------------------------------------------------------------
template<int PS>
__global__ __launch_bounds__(256) void k_stats2(const float* __restrict__ mI,
                                                const float* __restrict__ dep,
                                                float* __restrict__ maskf,
                                                float* __restrict__ smed,
                                                float* __restrict__ smaxA,
                                                float* __restrict__ sminA,
                                                int outn, int L)
{
    constexpr int HW = PS * PS;              // 16 or 64
    constexpr int TPB = 256 / HW;
    const int tok = blockIdx.x * TPB + threadIdx.x / HW;
    const int el  = threadIdx.x % HW;
    if (tok >= Bb * L) return;
    const int bi = tok / L, l = tok % L;
    const int ti = l / (outn * outn); const int rem = l % (outn * outn);
    const int oh = rem / outn, ow = rem % outn;
    const int n = bi * Tt + ti;
    const int py = el / PS, px = el % PS;
    const size_t off = (size_t)n * PIX + (size_t)(oh * PS + py) * 64 + ow * PS + px;
    const float mv = mI[off];
    const float dv = dep[off];
    float msum = mv, vmin = dv, vmax = dv;
#pragma unroll
    for (int o = HW / 2; o > 0; o >>= 1) {
        msum += __shfl_xor(msum, o);
        vmin = fminf(vmin, __shfl_xor(vmin, o));
        vmax = fmaxf(vmax, __shfl_xor(vmax, o));
    }
    const int gbase = (threadIdx.x & 63) & ~(HW - 1);
    int cl = 0, ce = 0;
#pragma unroll
    for (int b2 = 0; b2 < HW; ++b2) {
        float vb = __shfl(dv, gbase + b2);
        cl += (vb < dv);
        ce += (vb == dv);
    }
    constexpr int kk = (HW - 1) / 2;
    if (el == 0) {
        maskf[tok] = (msum / (float)HW > 0.5f) ? 1.f : 0.f;
        smaxA[tok] = 1.f / (1.f + __expf(-vmax));
        sminA[tok] = 1.f / (1.f + __expf(-vmin));
    }
    if (cl <= kk && kk < cl + ce)
        smed[tok] = 1.f / (1.f + __expf(-dv));
}

// ---------------------------------------------------------------------------
// Patch-extract bf16 -> bf16 [bi][l][f], 4 elements (=4 px) per thread.
// ---------------------------------------------------------------------------
__global__ void k_patch_bf(const u16* __restrict__ src, u16* __restrict__ dst,
                           int ps, int outn, int L, int F, int cbase)
{
    size_t idx = (size_t)blockIdx.x * 256 + threadIdx.x;
    size_t total = (size_t)Bb * L * F / 4;
    if (idx >= total) return;
    int f0 = (int)((idx * 4) % F);
    size_t t2 = (idx * 4) / F;
    int l = (int)(t2 % L);
    int bi = (int)(t2 / L);
    int hw = ps * ps;
    int ti = l / (outn * outn); int rem = l % (outn * outn);
    int oh = rem / outn, ow = rem % outn;
    int c = f0 / hw, r = f0 % hw;
    int py = r / ps, px = r % ps;
    int n = bi * Tt + ti;
    size_t si = ((size_t)n * Dc + cbase + c) * PIX + (oh * ps + py) * 64 + ow * ps + px;
    *(uint2*)&dst[((size_t)bi * L + l) * F + f0] = *(const uint2*)&src[si];
}

// V transposed patch: Vt[bi][f][l] bf16. 4 consecutive l per thread.
__global__ void k_patchT(const u16* __restrict__ v_bf, u16* __restrict__ Vt,
                         int ps, int outn, int L, int F, int cbase)
{
    size_t idx = (size_t)blockIdx.x * 256 + threadIdx.x;
    size_t total = (size_t)Bb * F * L / 4;
    if (idx >= total) return;
    int l0 = (int)((idx * 4) % L);
    size_t t2 = (idx * 4) / L;
    int f = (int)(t2 % F);
    int bi = (int)(t2 / F);
    int hw = ps * ps;
    int c = cbase + f / hw, r = f % hw;
    int py = r / ps, px = r % ps;
    int ti = l0 / (outn * outn); int rem = l0 % (outn * outn);
    int oh = rem / outn, ow0 = rem % outn;
    size_t base = ((size_t)(bi * Tt + ti) * Dc + c) * PIX + (oh * ps + py) * 64 + px;
    u16 out4[4];
#pragma unroll
    for (int e = 0; e < 4; ++e) out4[e] = v_bf[base + (size_t)(ow0 + e) * ps];
    *(uint2*)&Vt[((size_t)bi * F + f) * L + l0] = *(uint2*)out4;
}

// ---------------------------------------------------------------------------
// S = scale * Q K^T (pipelined register-direct), fp32 out, disjoint split-K
// partials; softmax sums them. grid (L/128, L/128, Bb*ksplit)
// ---------------------------------------------------------------------------
__global__ __launch_bounds__(256) void k_qkT_mfma(const u16* __restrict__ Qp,
                                                  const u16* __restrict__ Kp,
                                                  float* __restrict__ S,
                                                  int L, int F, int ksplit, float scale)
{
    const int tid = threadIdx.x, wave = tid >> 6, lane = tid & 63;
    const int bi = blockIdx.z / ksplit, ks = blockIdx.z % ksplit;
    const int kf = F / ksplit;
    f32x4 acc[4][4];
#pragma unroll
    for (int i = 0; i < 4; ++i)
#pragma unroll
        for (int j = 0; j < 4; ++j) acc[i][j] = (f32x4){0.f, 0.f, 0.f, 0.f};
    mfma_nt_pipe(Qp + (size_t)bi * L * F + (size_t)blockIdx.y * 128 * F + (size_t)ks * kf, F,
                 Kp + (size_t)bi * L * F + (size_t)blockIdx.x * 128 * F + (size_t)ks * kf, F,
                 kf / 32, wave, lane, acc);
    const int wm = (wave >> 1) * 64, wn = (wave & 1) * 64;
    const int rb = (lane >> 4) * 4, cb = lane & 15;
    float* Cp = S + ((size_t)ks * Bb + bi) * L * L;
#pragma unroll
    for (int i = 0; i < 4; ++i)
#pragma unroll
        for (int reg = 0; reg < 4; ++reg) {
            int gm = blockIdx.y * 128 + wm + i * 16 + rb + reg;
#pragma unroll
            for (int j = 0; j < 4; ++j) {
                int gn = blockIdx.x * 128 + wn + j * 16 + cb;
                Cp[(size_t)gm * L + gn] = acc[i][j][reg] * scale;
            }
        }
}

// ---------------------------------------------------------------------------
// 3-head softmax (sums NSPLIT partial S buffers), combined probs -> bf16 Pb.
// ---------------------------------------------------------------------------
__device__ inline float blockMax(float v, float* sh) {
#pragma unroll
    for (int o = 32; o > 0; o >>= 1) v = fmaxf(v, __shfl_down(v, o));
    __syncthreads();
    if ((threadIdx.x & 63) == 0) sh[threadIdx.x >> 6] = v;
    __syncthreads();
    return fmaxf(fmaxf(sh[0], sh[1]), fmaxf(sh[2], sh[3]));
}
__device__ inline float blockSum(float v, float* sh) {
#pragma unroll
    for (int o = 32; o > 0; o >>= 1) v += __shfl_down(v, o);
    __syncthreads();
    if ((threadIdx.x & 63) == 0) sh[threadIdx.x >> 6] = v;
    __syncthreads();
    return sh[0] + sh[1] + sh[2] + sh[3];
}

template<int NV, int NSPLIT>
__global__ __launch_bounds__(256) void k_softmax(const float* __restrict__ S,
                                                 u16* __restrict__ Pb,
                                                 const float* __restrict__ maskf,
                                                 const float* __restrict__ smed,
                                                 const float* __restrict__ smaxA,
                                                 const float* __restrict__ sminA,
                                                 int L)
{
    __shared__ float sred[4];
    const int bi = blockIdx.y, q = blockIdx.x;
    const size_t pstr = (size_t)Bb * L * L;
    const float* row = S + (size_t)bi * L * L + (size_t)q * L;
    u16* prow = Pb + (size_t)bi * L * L + (size_t)q * L;
    const float* mk  = maskf + bi * L;
    const float* s0p = smed  + bi * L;
    const float* s1p = smaxA + bi * L;
    const float* s2p = sminA + bi * L;
    const int tid = threadIdx.x;
    float a0[NV], a1[NV], a2[NV];
    float m0 = -3.4e38f, m1 = -3.4e38f, m2 = -3.4e38f;
#pragma unroll
    for (int e = 0; e < NV; ++e) {
        int k = e * 256 + tid;
        float sv = row[k];
#pragma unroll
        for (int s2 = 1; s2 < NSPLIT; ++s2) sv += row[(size_t)s2 * pstr + k];
        bool msk = mk[k] > 0.5f;
        float v0 = msk ? -1e9f : sv * s0p[k];
        float v1 = msk ? -1e9f : sv * s1p[k];
        float v2 = msk ? -1e9f : sv * s2p[k];
        a0[e] = v0; a1[e] = v1; a2[e] = v2;
        m0 = fmaxf(m0, v0); m1 = fmaxf(m1, v1); m2 = fmaxf(m2, v2);
    }
    m0 = blockMax(m0, sred); m1 = blockMax(m1, sred); m2 = blockMax(m2, sred);
    float l0 = 0.f, l1 = 0.f, l2 = 0.f;
#pragma unroll
    for (int e = 0; e < NV; ++e) {
        a0[e] = __expf(a0[e] - m0); l0 += a0[e];
        a1[e] = __expf(a1[e] - m1); l1 += a1[e];
        a2[e] = __expf(a2[e] - m2); l2 += a2[e];
    }
    l0 = blockSum(l0, sred); l1 = blockSum(l1, sred); l2 = blockSum(l2, sred);
    float c0 = 1.f / (3.f * l0), c1 = 1.f / (3.f * l1), c2 = 1.f / (3.f * l2);
#pragma unroll
    for (int e = 0; e < NV; ++e)
        prow[e * 256 + tid] = f2bf(a0[e] * c0 + a1[e] * c1 + a2[e] * c2);
}

// ---------------------------------------------------------------------------
// Y = P @ V (pipelined register-direct, split-K). Partials -> coalesced bf16
// rows Yp[ks][bi][l][f]; NHWC scatter deferred to k_unpatch.
// grid (F/128, L/128, Bb*ksplit)
// ---------------------------------------------------------------------------
__global__ __launch_bounds__(256) void k_pv_mfma(const u16* __restrict__ Pb,
                                                 const u16* __restrict__ Vt,
                                                 u16* __restrict__ Yp,
                                                 int L, int F, int ksplit)
{
    const int tid = threadIdx.x, wave = tid >> 6, lane = tid & 63;
    const int bi = blockIdx.z / ksplit, ks = blockIdx.z % ksplit;
    const int kf = L / ksplit;
    f32x4 acc[4][4];
#pragma unroll
    for (int i = 0; i < 4; ++i)
#pragma unroll
        for (int j = 0; j < 4; ++j) acc[i][j] = (f32x4){0.f, 0.f, 0.f, 0.f};
    mfma_nt_pipe(Pb + (size_t)bi * L * L + (size_t)blockIdx.y * 128 * L + (size_t)ks * kf, L,
                 Vt + (size_t)bi * F * L + (size_t)blockIdx.x * 128 * L + (size_t)ks * kf, L,
                 kf / 32, wave, lane, acc);
    const int wm = (wave >> 1) * 64, wn = (wave & 1) * 64;
    const int rb = (lane >> 4) * 4, cb = lane & 15;
    u16* Cp = Yp + ((size_t)(ks * Bb + bi) * L) * F;
#pragma unroll
    for (int i = 0; i < 4; ++i)
#pragma unroll
        for (int reg = 0; reg < 4; ++reg) {
            int gm = blockIdx.y * 128 + wm + i * 16 + rb + reg;
#pragma unroll
            for (int j = 0; j < 4; ++j) {
                int gn = blockIdx.x * 128 + wn + j * 16 + cb;
                Cp[(size_t)gm * F + gn] = f2bf(acc[i][j][reg]);
            }
        }
}

// ---------------------------------------------------------------------------
// Sum NSPLIT Yp partials + scatter to catbT[pix][cin].
// ---------------------------------------------------------------------------
template<int NSPLIT>
__global__ void k_unpatch(const u16* __restrict__ Yp, u16* __restrict__ catbT,
                          int ps, int outn, int L, int F, int cbase)
{
    size_t idx = (size_t)blockIdx.x * 256 + threadIdx.x;
    size_t total = (size_t)Bb * L * F / 4;
    if (idx >= total) return;
    const size_t pstr = (size_t)Bb * L * F;
    int f0 = (int)((idx * 4) % F);
    size_t t2 = (idx * 4) / F;
    int l = (int)(t2 % L);
    int bi = (int)(t2 / L);
    size_t off = ((size_t)bi * L + l) * F + f0;
    float s[4] = {0.f, 0.f, 0.f, 0.f};
#pragma unroll
    for (int sp = 0; sp < NSPLIT; ++sp) {
        uint2 u = *(const uint2*)&Yp[(size_t)sp * pstr + off];
        s[0] += bf2f((u16)(u.x & 0xffffu));
        s[1] += bf2f((u16)(u.x >> 16));
        s[2] += bf2f((u16)(u.y & 0xffffu));
        s[3] += bf2f((u16)(u.y >> 16));
    }
    int hw = ps * ps;
    int c = cbase + f0 / hw, r0 = f0 % hw;
    int ti = l / (outn * outn); int rem = l % (outn * outn);
    int oh = rem / outn, ow = rem % outn;
    int n = bi * Tt + ti;
    int py = r0 / ps, px = r0 % ps;   // r0 4-aligned -> same row, 4 consecutive px
    size_t base = ((size_t)n * PIX + (size_t)(oh * ps + py) * 64 + ow * ps + px) * Dc + c;
#pragma unroll
    for (int e = 0; e < 4; ++e)
        catbT[base + (size_t)e * Dc] = f2bf(s[e]);
}

// ---------------------------------------------------------------------------
// Output conv 3x3 as 9-tap implicit NT GEMM, 4-slot pipelined over the 36
// flattened (tap,kb) chunks; OOB lanes read a zero page. float4 stores.
// grid (512 pixel tiles)
// ---------------------------------------------------------------------------
__global__ __launch_bounds__(256) void k_conv_mfma(const u16* __restrict__ catbT,
                                                   const u16* __restrict__ WoT,
                                                   const float* __restrict__ bo,
                                                   const u16* __restrict__ zp,
                                                   float* __restrict__ outp)
{
    const int tid = threadIdx.x, wave = tid >> 6, lane = tid & 63;
    const int pix0 = blockIdx.x * 128;
    const int wm = (wave >> 1) * 64, wn = (wave & 1) * 64;
    const int fr = lane & 15, kq = (lane >> 4) * 8;
    int py[4], px[4];
    const u16* Abase[4];
#pragma unroll
    for (int i = 0; i < 4; ++i) {
        int pg = pix0 + wm + i * 16 + fr;
        py[i] = (pg >> 6) & 63; px[i] = pg & 63;
        Abase[i] = catbT + (((size_t)(pg >> 12)) << 19) + kq;   // (n*4096)*128
    }
    const u16* Bbase = WoT + (size_t)(wn + fr) * 128 + kq;
    f32x4 acc[4][4];
#pragma unroll
    for (int i = 0; i < 4; ++i)
#pragma unroll
        for (int j = 0; j < 4; ++j) acc[i][j] = (f32x4){0.f, 0.f, 0.f, 0.f};

    bf16x8 aq[4][4], bq[4][4];
    auto refill = [&](int s, int t) {
        int tap = t >> 2, kb2 = (t & 3) * 32;
        int dy = tap / 3 - 1, dx = tap % 3 - 1;
#pragma unroll
        for (int i = 0; i < 4; ++i) {
            int y = py[i] + dy, xx = px[i] + dx;
            bool ok = ((unsigned)y < 64u) && ((unsigned)xx < 64u);
            const u16* ap = ok ? (Abase[i] + (size_t)(y * 64 + xx) * 128 + kb2) : zp;
            aq[s][i] = *(const bf16x8*)ap;
        }
        const u16* bp = Bbase + tap * 16384 + kb2;
#pragma unroll
        for (int j = 0; j < 4; ++j)
            bq[s][j] = *(const bf16x8*)(bp + j * 2048);
    };
    refill(0, 0); refill(1, 1); refill(2, 2); refill(3, 3);
    for (int t0 = 0; t0 < 36; t0 += 4) {
#pragma unroll
        for (int s = 0; s < 4; ++s) {
#pragma unroll
            for (int i = 0; i < 4; ++i)
#pragma unroll
                for (int j = 0; j < 4; ++j)
                    acc[i][j] = __builtin_amdgcn_mfma_f32_16x16x32_bf16(aq[s][i], bq[s][j], acc[i][j], 0, 0, 0);
            if (t0 + s + 4 < 36) refill(s, t0 + s + 4);
        }
    }
    const int rb = (lane >> 4) * 4, cb = lane & 15;
#pragma unroll
    for (int j = 0; j < 4; ++j) {
        int cout = wn + j * 16 + cb;
        float bias = bo[cout];
#pragma unroll
        for (int i = 0; i < 4; ++i) {
            int pb = pix0 + wm + i * 16 + rb;
            int n = pb >> 12, p = pb & 4095;
            f32x4 v;
#pragma unroll
            for (int reg = 0; reg < 4; ++reg) {
                float w = acc[i][j][reg] + bias;
                v[reg] = (w >= 0.f) ? w : 0.2f * w;
            }
            *(f32x4*)&outp[((size_t)n * Dc + cout) * PIX + p] = v;
        }
    }
}

// ---------------------------------------------------------------------------
extern "C" void kernel_launch(void* const* d_in, const int* in_sizes, int n_in,
                              void* d_out, int out_size, void* d_ws, size_t ws_size,
                              hipStream_t stream)
{
    (void)in_sizes; (void)n_in; (void)out_size; (void)ws_size;
    const float* x    = (const float*)d_in[0];
    const float* mI   = (const float*)d_in[1];
    const float* dmap = (const float*)d_in[2];
    const float* wq   = (const float*)d_in[3];
    const float* bq   = (const float*)d_in[4];
    const float* wk   = (const float*)d_in[5];
    const float* bk   = (const float*)d_in[6];
    const float* wv   = (const float*)d_in[7];
    const float* bv   = (const float*)d_in[8];
    const float* wvle = (const float*)d_in[9];
    const float* bvle = (const float*)d_in[10];
    const float* wd1  = (const float*)d_in[11];
    const float* bd1  = (const float*)d_in[12];
    const float* wd2  = (const float*)d_in[13];
    const float* bd2  = (const float*)d_in[14];
    const float* wo   = (const float*)d_in[15];
    const float* bo   = (const float*)d_in[16];

    // workspace layout (~190 MB)
    char* w8 = (char*)d_ws;
    u16*   q_bf  = (u16*)(w8);                    // 16 MB each
    u16*   k_bf  = (u16*)(w8 + 0x1000000);
    u16*   v_bf  = (u16*)(w8 + 0x2000000);
    u16*   Xt    = (u16*)(w8 + 0x3000000);
    u16*   catbT = (u16*)(w8 + 0x4000000);
    u16*   Qp    = (u16*)(w8 + 0x5000000);        // 8 MB each
    u16*   Kp    = (u16*)(w8 + 0x5800000);
    u16*   Vt    = (u16*)(w8 + 0x6000000);
    float* Sb    = (float*)(w8 + 0x6800000);      // 32 MB (i=0: 2x16MB; i=1: 16x2MB)
    u16*   Yp    = (u16*)(w8 + 0x8800000);        // 32 MB (pv split partials)
    u16*   Pb    = (u16*)(w8 + 0xA800000);        // 16 MB
    // d1b (67 MB) ALIASES Qp..Yp: depth path runs strictly before the attn loop
    u16*   d1b   = (u16*)(w8 + 0x5000000);
    float* dep   = (float*)(w8 + 0xB800000);
    float* maskf = (float*)(w8 + 0xB840000);
    float* smed  = (float*)(w8 + 0xB844000);
    float* smaxA = (float*)(w8 + 0xB848000);
    float* sminA = (float*)(w8 + 0xB84C000);
    u16*   Wqkv  = (u16*)(w8 + 0xB850000);
    u16*   WoT   = (u16*)(w8 + 0xB868000);
    u16*   zp    = (u16*)(w8 + 0xB8B0000);
    float* part  = (float*)(w8 + 0xB8C0000);      // 2 MB
    float* outp  = (float*)d_out;

    hipMemcpyAsync(outp + 8388608, dmap, (size_t)16 * 65536 * sizeof(float),
                   hipMemcpyDeviceToDevice, stream);
    hipMemsetAsync(zp, 0, 256, stream);

    dim3 blk(256);
    // depth path first (d1b aliases attention scratch)
    k_d1<<<dim3(32, 16), blk, 0, stream>>>(dmap, wd1, bd1, d1b);
    k_d2p<<<dim3(4, 16, 8), blk, 0, stream>>>(d1b, wd2, part);
    k_dfin<<<dim3(256), blk, 0, stream>>>(part, bd2, dep);

    k_prep<<<dim3(768), blk, 0, stream>>>(wq, wk, wv, wo, Wqkv, WoT);
    k_xt<<<dim3(64, 16), blk, 0, stream>>>(x, Xt);
    k_qkv_mfma<<<dim3(32, 3, 16), blk, 0, stream>>>(Wqkv, Xt, bq, bk, bv, q_bf, k_bf, v_bf);
    k_vdw<<<dim3(16, 128, 16), blk, 0, stream>>>(x, wvle, bvle, v_bf);

    for (int i = 0; i < 2; ++i) {
        const int ps = (i == 0) ? 4 : 8;
        const int outn = 64 / ps;
        const int L = Tt * outn * outn;        // 2048 / 512
        const int F = 64 * ps * ps;            // 1024 / 4096
        const int cbase = i * 64;
        const float scale = 1.0f / sqrtf((float)F);
        const int ksplit  = (i == 0) ? 1 : 16; // qkT split (i=1: 512 blocks)
        const int pvsplit = (i == 0) ? 4 : 2;  // pv split (i=0: 1024 blocks)

        if (i == 0) k_stats2<4><<<dim3(Bb * L * 16 / 256), blk, 0, stream>>>(mI, dep, maskf, smed, smaxA, sminA, outn, L);
        else        k_stats2<8><<<dim3(Bb * L * 64 / 256), blk, 0, stream>>>(mI, dep, maskf, smed, smaxA, sminA, outn, L);

        const int pgrid = (int)(((size_t)Bb * L * F / 4 + 255) / 256);
        k_patch_bf<<<dim3(pgrid), blk, 0, stream>>>(q_bf, Qp, ps, outn, L, F, cbase);
        k_patch_bf<<<dim3(pgrid), blk, 0, stream>>>(k_bf, Kp, ps, outn, L, F, cbase);
        k_patchT<<<dim3(pgrid), blk, 0, stream>>>(v_bf, Vt, ps, outn, L, F, cbase);

        k_qkT_mfma<<<dim3(L / 128, L / 128, Bb * ksplit), blk, 0, stream>>>(Qp, Kp, Sb, L, F, ksplit, scale);

        if (i == 0) k_softmax<8, 1><<<dim3(L, Bb), blk, 0, stream>>>(Sb, Pb, maskf, smed, smaxA, sminA, L);
        else        k_softmax<2, 16><<<dim3(L, Bb), blk, 0, stream>>>(Sb, Pb, maskf, smed, smaxA, sminA, L);

        k_pv_mfma<<<dim3(F / 128, L / 128, Bb * pvsplit), blk, 0, stream>>>(Pb, Vt, Yp, L, F, pvsplit);
        if (i == 0) k_unpatch<4><<<dim3(pgrid), blk, 0, stream>>>(Yp, catbT, ps, outn, L, F, cbase);
        else        k_unpatch<2><<<dim3(pgrid), blk, 0, stream>>>(Yp, catbT, ps, outn, L, F, cbase);
    }

    k_conv_mfma<<<dim3(512), blk, 0, stream>>>(catbT, WoT, bo, zp, outp);
}

// Round 7
// 543.094 us; speedup vs baseline: 1.1829x; 1.1829x over previous
//
#include <hip/hip_runtime.h>
#include <cmath>

typedef unsigned short u16;
typedef __attribute__((ext_vector_type(8))) __bf16 bf16x8;
typedef __attribute__((ext_vector_type(4))) float f32x4;

constexpr int Bb = 2, Tt = 8, Dc = 128, PIX = 4096; // b=2, c=128, 64x64 imgs

__device__ inline u16 f2bf(float f) {
    unsigned u = __builtin_bit_cast(unsigned, f);
    u += 0x7fffu + ((u >> 16) & 1u);
    return (u16)(u >> 16);
}
__device__ inline float bf2f(u16 h) {
    unsigned u = ((unsigned)h) << 16;
    return __builtin_bit_cast(float, u);
}

#define GLOAD16(gp, lp) __builtin_amdgcn_global_load_lds( \
    (const __attribute__((address_space(1))) void*)(const void*)(gp), \
    (__attribute__((address_space(3))) void*)(void*)(lp), 16, 0, 0)

// ---------------------------------------------------------------------------
// bf16 NT MFMA core (m97 pattern): C(128x128) = A(128xK)*B(128xK)^T.
// LDS [row][kseg], XOR swizzle (seg ^= (row>>1)&3) -> measured 0 bank
// conflicts. VGPR ~80, LDS 16KB -> up to 6 waves/SIMD, 10 blocks/CU.
// KEY LESSON (r4-r6): this core measures ~9% MfmaUtil at 1-2 blocks/CU and
// m97 measures 37% at 3+ blocks/CU -- occupancy (TLP across blocks), not
// intra-wave pipelining, is what hides the staging latency. The compiler
// defeats manual register pipelines (r6: VGPR 132 proves queue collapsed).
// All callers now launch >=1024 blocks (4 blocks/CU).
// ---------------------------------------------------------------------------
__device__ inline void mfma_chunk(const u16* lAs, const u16* lBs, int wave, int lane,
                                  f32x4 (&acc)[4][4])
{
    const int wm = (wave >> 1) * 64, wn = (wave & 1) * 64;
    const int fr = lane & 15;
    const int q4 = lane >> 4;                         // wanted global k-quarter
    const int sw = (q4 ^ ((fr >> 1) & 3)) * 8;        // swizzled storage seg
    bf16x8 av[4], bv[4];
#pragma unroll
    for (int i = 0; i < 4; ++i) av[i] = *(const bf16x8*)&lAs[(wm + i * 16 + fr) * 32 + sw];
#pragma unroll
    for (int j = 0; j < 4; ++j) bv[j] = *(const bf16x8*)&lBs[(wn + j * 16 + fr) * 32 + sw];
#pragma unroll
    for (int i = 0; i < 4; ++i)
#pragma unroll
        for (int j = 0; j < 4; ++j)
            acc[i][j] = __builtin_amdgcn_mfma_f32_16x16x32_bf16(av[i], bv[j], acc[i][j], 0, 0, 0);
}

__device__ inline void mfma_nt(const u16* A, int ldkA, const u16* B, int ldkB,
                               int kChunks, int wave, int lane,
                               u16* lAs, u16* lBs, f32x4 (&acc)[4][4])
{
    const int r = lane >> 2;                              // row within 16-group
    const int kq8 = ((lane & 3) ^ ((r >> 1) & 3)) * 8;    // swizzled source seg
    const u16* ga0 = A + (size_t)(wave * 32 + r) * ldkA + kq8;
    const u16* ga1 = ga0 + (size_t)16 * ldkA;
    const u16* gb0 = B + (size_t)(wave * 32 + r) * ldkB + kq8;
    const u16* gb1 = gb0 + (size_t)16 * ldkB;
    for (int kb = 0; kb < kChunks; ++kb) {
        __syncthreads();                       // WAR: prior chunk's ds_reads done
        GLOAD16(ga0 + kb * 32, lAs + wave * 1024);
        GLOAD16(ga1 + kb * 32, lAs + wave * 1024 + 512);
        GLOAD16(gb0 + kb * 32, lBs + wave * 1024);
        GLOAD16(gb1 + kb * 32, lBs + wave * 1024 + 512);
        __syncthreads();                       // drains vmcnt(0) before barrier
        mfma_chunk(lAs, lBs, wave, lane, acc);
    }
}

// ---------------------------------------------------------------------------
// Weight prep: Wqkv[3*128][128] bf16 stacked; WoT[tap][cout][cin] bf16.
// ---------------------------------------------------------------------------
__global__ void k_prep(const float* __restrict__ wq, const float* __restrict__ wk,
                       const float* __restrict__ wv, const float* __restrict__ wo,
                       u16* __restrict__ Wqkv, u16* __restrict__ WoT)
{
    int idx = blockIdx.x * 256 + threadIdx.x;
    if (idx < 49152) {
        const float* w = idx < 16384 ? wq : (idx < 32768 ? wk : wv);
        Wqkv[idx] = f2bf(w[idx & 16383]);
    }
    int j = idx - 49152;
    if (j >= 0 && j < 147456) {
        int tap = j / 16384, rem = j % 16384;  // rem = cout*128+cin
        WoT[j] = f2bf(wo[(size_t)rem * 9 + tap]);
    }
}

// ---------------------------------------------------------------------------
// Xt[n][pix][cin] bf16 from x[n][cin][pix] fp32 (LDS transpose, 64-pix tiles)
// ---------------------------------------------------------------------------
__global__ __launch_bounds__(256) void k_xt(const float* __restrict__ x, u16* __restrict__ Xt)
{
    __shared__ float ls[128 * 65];
    const int n = blockIdx.y, pix0 = blockIdx.x * 64;
#pragma unroll
    for (int rep = 0; rep < 32; ++rep) {
        int idx = rep * 256 + threadIdx.x;
        int cin = idx >> 6, p = idx & 63;
        ls[cin * 65 + p] = x[((size_t)n * Dc + cin) * PIX + pix0 + p];
    }
    __syncthreads();
#pragma unroll
    for (int rep = 0; rep < 32; ++rep) {
        int idx = rep * 256 + threadIdx.x;
        int p = idx >> 7, cin = idx & 127;
        Xt[((size_t)n * PIX + pix0 + p) * Dc + cin] = f2bf(ls[cin * 65 + p]);
    }
}

// ---------------------------------------------------------------------------
// Fused QKV: C[384][4096] = Wqkv * Xt^T per image; bf16 out + bias, routed.
// grid (32 pixtiles, 3 Mtiles, 16 imgs) = 1536 blocks (6 blocks/CU).
// ---------------------------------------------------------------------------
__global__ __launch_bounds__(256) void k_qkv_mfma(const u16* __restrict__ Wqkv,
                                                  const u16* __restrict__ Xt,
                                                  const float* __restrict__ bq,
                                                  const float* __restrict__ bk,
                                                  const float* __restrict__ bv,
                                                  u16* __restrict__ q_bf,
                                                  u16* __restrict__ k_bf,
                                                  u16* __restrict__ v_bf)
{
    __shared__ u16 lAs[4096], lBs[4096];
    const int tid = threadIdx.x, wave = tid >> 6, lane = tid & 63;
    const int mt = blockIdx.y, n = blockIdx.z, px0 = blockIdx.x * 128;
    f32x4 acc[4][4];
#pragma unroll
    for (int i = 0; i < 4; ++i)
#pragma unroll
        for (int j = 0; j < 4; ++j) acc[i][j] = (f32x4){0.f, 0.f, 0.f, 0.f};
    mfma_nt(Wqkv + (size_t)mt * 128 * 128, 128,
            Xt + ((size_t)n * PIX + px0) * 128, 128, 4, wave, lane, lAs, lBs, acc);
    const int wm = (wave >> 1) * 64, wn = (wave & 1) * 64;
    const int rb = (lane >> 4) * 4, cb = lane & 15;
#pragma unroll
    for (int i = 0; i < 4; ++i)
#pragma unroll
        for (int reg = 0; reg < 4; ++reg) {
            int gmg = mt * 128 + wm + i * 16 + rb + reg;     // stacked cout 0..383
            int sel = gmg >> 7, c = gmg & 127;
            float bias = (sel == 0 ? bq : sel == 1 ? bk : bv)[c];
            u16* dst = (sel == 0 ? q_bf : sel == 1 ? k_bf : v_bf);
#pragma unroll
            for (int j = 0; j < 4; ++j) {
                int pix = px0 + wn + j * 16 + cb;
                dst[((size_t)n * Dc + c) * PIX + pix] = f2bf(acc[i][j][reg] + bias);
            }
        }
}

// ---------------------------------------------------------------------------
// depthwise 3x3 add into bf16 v_all. grid (16, 128, 16)
// ---------------------------------------------------------------------------
__global__ __launch_bounds__(256) void k_vdw(const float* __restrict__ X,
                                             const float* __restrict__ wvle,
                                             const float* __restrict__ bvle,
                                             u16* __restrict__ v_bf)
{
    const int n = blockIdx.z, c = blockIdx.y;
    const int p = blockIdx.x * 256 + threadIdx.x;
    const int y = p >> 6, x = p & 63;
    const float* xp = X + ((size_t)n * Dc + c) * PIX;
    const float* w  = wvle + c * 9;
    float s = bvle[c];
#pragma unroll
    for (int ky = 0; ky < 3; ++ky) {
        int yy = y + ky - 1;
        if (yy < 0 || yy >= 64) continue;
#pragma unroll
        for (int kx = 0; kx < 3; ++kx) {
            int xx = x + kx - 1;
            if (xx < 0 || xx >= 64) continue;
            s += w[ky * 3 + kx] * xp[yy * 64 + xx];
        }
    }
    size_t idx = ((size_t)n * Dc + c) * PIX + p;
    v_bf[idx] = f2bf(bf2f(v_bf[idx]) + s);
}

// ---------------------------------------------------------------------------
// Depth path, kernel 1: d1[n][c][128][128] = relu(conv(dm, wd1, s2, p1)) bf16.
// ---------------------------------------------------------------------------
__global__ __launch_bounds__(256) void k_d1(const float* __restrict__ dm,
                                            const float* __restrict__ wd1,
                                            const float* __restrict__ bd1,
                                            u16* __restrict__ d1b)
{
    __shared__ float ls[17 * 132];
    const int n = blockIdx.y;
    const int yt = blockIdx.x >> 1, xh = blockIdx.x & 1;
    const int Y0 = yt * 8;
    const int tid = threadIdx.x;
    const float* dmp = dm + (size_t)n * 65536;
    for (int idx = tid; idx < 17 * 132; idx += 256) {
        int row = idx / 132, cl = idx % 132;
        int gr = 2 * Y0 - 1 + row;
        int gc = 128 * xh - 1 + cl;
        float v = 0.f;
        if (gr >= 0 && gr < 256 && gc >= 0 && gc < 256 && cl < 129) v = dmp[gr * 256 + gc];
        ls[idx] = v;
    }
    __syncthreads();
    const int Xl = tid & 63;
    const int Yl0 = tid >> 6;                 // rows Yl0 and Yl0+4
    float in0[9], in1[9];
#pragma unroll
    for (int jy = 0; jy < 3; ++jy)
#pragma unroll
        for (int jx = 0; jx < 3; ++jx) {
            in0[jy * 3 + jx] = ls[(2 * Yl0 + jy) * 132 + 2 * Xl + jx];
            in1[jy * 3 + jx] = ls[(2 * (Yl0 + 4) + jy) * 132 + 2 * Xl + jx];
        }
    const int X = 64 * xh + Xl;
    u16* outbase = d1b + (size_t)n * Dc * 16384 + (size_t)Y0 * 128 + X;
    for (int c = 0; c < 128; ++c) {
        const float* w1 = wd1 + c * 9;        // uniform -> s_load
        float a0 = bd1[c], a1 = a0;
#pragma unroll
        for (int t = 0; t < 9; ++t) { a0 += w1[t] * in0[t]; a1 += w1[t] * in1[t]; }
        u16* ob = outbase + (size_t)c * 16384;
        ob[(size_t)Yl0 * 128]       = f2bf(fmaxf(a0, 0.f));
        ob[(size_t)(Yl0 + 4) * 128] = f2bf(fmaxf(a1, 0.f));
    }
}

// ---------------------------------------------------------------------------
// Depth path, kernel 2: partial conv2 over 16-channel groups.
// ---------------------------------------------------------------------------
__global__ __launch_bounds__(256) void k_d2p(const u16* __restrict__ d1b,
                                             const float* __restrict__ wd2,
                                             float* __restrict__ part)
{
    __shared__ u16 ls[33 * 136];              // payload at cl 8..135, zero at cl 7
    const int yt = blockIdx.x, n = blockIdx.y, cg = blockIdx.z;
    const int tid = threadIdx.x;
    const int y0 = yt * 16;
    if (tid < 33) ls[tid * 136 + 7] = 0;
    const int x = tid & 63;
    const int yl0 = (tid >> 6) * 4;
    float acc[4] = {0.f, 0.f, 0.f, 0.f};
    for (int c = 0; c < 16; ++c) {
        const u16* src = d1b + ((size_t)n * Dc + cg * 16 + c) * 16384;
        __syncthreads();
        for (int idx = tid; idx < 33 * 16; idx += 256) {
            int row = idx >> 4, s = idx & 15;
            int gr = 2 * y0 - 1 + row;
            uint4 v = make_uint4(0, 0, 0, 0);
            if (gr >= 0 && gr < 128) v = *(const uint4*)(src + gr * 128 + s * 8);
            *(uint4*)&ls[row * 136 + 8 + s * 8] = v;
        }
        __syncthreads();
        const float* w2 = wd2 + (cg * 16 + c) * 9;   // uniform -> s_load
        float w[9];
#pragma unroll
        for (int t = 0; t < 9; ++t) w[t] = w2[t];
#pragma unroll
        for (int r = 0; r < 4; ++r) {
            int yl = yl0 + r;
#pragma unroll
            for (int ky = 0; ky < 3; ++ky) {
                const u16* rp = &ls[(2 * yl + ky) * 136 + 2 * x + 7];
                float v0 = bf2f(rp[0]);
                unsigned pr = *(const unsigned*)(rp + 1);
                float v1 = bf2f((u16)(pr & 0xffffu));
                float v2 = bf2f((u16)(pr >> 16));
                acc[r] += w[ky * 3 + 0] * v0 + w[ky * 3 + 1] * v1 + w[ky * 3 + 2] * v2;
            }
        }
    }
    float* pp = part + ((size_t)cg * 16 + n) * PIX;
#pragma unroll
    for (int r = 0; r < 4; ++r)
        pp[(y0 + yl0 + r) * 64 + x] = acc[r];
}

// Depth path, kernel 3: dep = relu(sum_cg part + bd2). grid (256)
__global__ void k_dfin(const float* __restrict__ part, const float* __restrict__ bd2,
                       float* __restrict__ dep)
{
    int idx = blockIdx.x * 256 + threadIdx.x;
    float s = bd2[0];
#pragma unroll
    for (int cg = 0; cg < 8; ++cg) s += part[(size_t)cg * 65536 + idx];
    dep[idx] = fmaxf(s, 0.f);
}

// ---------------------------------------------------------------------------
// Wave-parallel per-token stats (min/max/mask butterfly, exact median rank).
// ---------------------------------------------------------------------------
template<int PS>
__global__ __launch_bounds__(256) void k_stats2(const float* __restrict__ mI,
                                                const float* __restrict__ dep,
                                                float* __restrict__ maskf,
                                                float* __restrict__ smed,
                                                float* __restrict__ smaxA,
                                                float* __restrict__ sminA,
                                                int outn, int L)
{
    constexpr int HW = PS * PS;              // 16 or 64
    constexpr int TPB = 256 / HW;
    const int tok = blockIdx.x * TPB + threadIdx.x / HW;
    const int el  = threadIdx.x % HW;
    if (tok >= Bb * L) return;
    const int bi = tok / L, l = tok % L;
    const int ti = l / (outn * outn); const int rem = l % (outn * outn);
    const int oh = rem / outn, ow = rem % outn;
    const int n = bi * Tt + ti;
    const int py = el / PS, px = el % PS;
    const size_t off = (size_t)n * PIX + (size_t)(oh * PS + py) * 64 + ow * PS + px;
    const float mv = mI[off];
    const float dv = dep[off];
    float msum = mv, vmin = dv, vmax = dv;
#pragma unroll
    for (int o = HW / 2; o > 0; o >>= 1) {
        msum += __shfl_xor(msum, o);
        vmin = fminf(vmin, __shfl_xor(vmin, o));
        vmax = fmaxf(vmax, __shfl_xor(vmax, o));
    }
    const int gbase = (threadIdx.x & 63) & ~(HW - 1);
    int cl = 0, ce = 0;
#pragma unroll
    for (int b2 = 0; b2 < HW; ++b2) {
        float vb = __shfl(dv, gbase + b2);
        cl += (vb < dv);
        ce += (vb == dv);
    }
    constexpr int kk = (HW - 1) / 2;
    if (el == 0) {
        maskf[tok] = (msum / (float)HW > 0.5f) ? 1.f : 0.f;
        smaxA[tok] = 1.f / (1.f + __expf(-vmax));
        sminA[tok] = 1.f / (1.f + __expf(-vmin));
    }
    if (cl <= kk && kk < cl + ce)
        smed[tok] = 1.f / (1.f + __expf(-dv));
}

// ---------------------------------------------------------------------------
// Patch-extract bf16 -> bf16 [bi][l][f], 4 elements (=4 px) per thread.
// ---------------------------------------------------------------------------
__global__ void k_patch_bf(const u16* __restrict__ src, u16* __restrict__ dst,
                           int ps, int outn, int L, int F, int cbase)
{
    size_t idx = (size_t)blockIdx.x * 256 + threadIdx.x;
    size_t total = (size_t)Bb * L * F / 4;
    if (idx >= total) return;
    int f0 = (int)((idx * 4) % F);
    size_t t2 = (idx * 4) / F;
    int l = (int)(t2 % L);
    int bi = (int)(t2 / L);
    int hw = ps * ps;
    int ti = l / (outn * outn); int rem = l % (outn * outn);
    int oh = rem / outn, ow = rem % outn;
    int c = f0 / hw, r = f0 % hw;
    int py = r / ps, px = r % ps;
    int n = bi * Tt + ti;
    size_t si = ((size_t)n * Dc + cbase + c) * PIX + (oh * ps + py) * 64 + ow * ps + px;
    *(uint2*)&dst[((size_t)bi * L + l) * F + f0] = *(const uint2*)&src[si];
}

// V transposed patch: Vt[bi][f][l] bf16. 4 consecutive l per thread.
__global__ void k_patchT(const u16* __restrict__ v_bf, u16* __restrict__ Vt,
                         int ps, int outn, int L, int F, int cbase)
{
    size_t idx = (size_t)blockIdx.x * 256 + threadIdx.x;
    size_t total = (size_t)Bb * F * L / 4;
    if (idx >= total) return;
    int l0 = (int)((idx * 4) % L);
    size_t t2 = (idx * 4) / L;
    int f = (int)(t2 % F);
    int bi = (int)(t2 / F);
    int hw = ps * ps;
    int c = cbase + f / hw, r = f % hw;
    int py = r / ps, px = r % ps;
    int ti = l0 / (outn * outn); int rem = l0 % (outn * outn);
    int oh = rem / outn, ow0 = rem % outn;
    size_t base = ((size_t)(bi * Tt + ti) * Dc + c) * PIX + (oh * ps + py) * 64 + px;
    u16 out4[4];
#pragma unroll
    for (int e = 0; e < 4; ++e) out4[e] = v_bf[base + (size_t)(ow0 + e) * ps];
    *(uint2*)&Vt[((size_t)bi * F + f) * L + l0] = *(uint2*)out4;
}

// ---------------------------------------------------------------------------
// S = scale * Q K^T (LDS MFMA), fp32 out; disjoint split-K partials.
// grid (L/128, L/128, Bb*ksplit) -- ksplit chosen so grid >= 1024.
// ---------------------------------------------------------------------------
__global__ __launch_bounds__(256) void k_qkT_mfma(const u16* __restrict__ Qp,
                                                  const u16* __restrict__ Kp,
                                                  float* __restrict__ S,
                                                  int L, int F, int ksplit, float scale)
{
    __shared__ u16 lAs[4096], lBs[4096];
    const int tid = threadIdx.x, wave = tid >> 6, lane = tid & 63;
    const int bi = blockIdx.z / ksplit, ks = blockIdx.z % ksplit;
    const int kf = F / ksplit;
    f32x4 acc[4][4];
#pragma unroll
    for (int i = 0; i < 4; ++i)
#pragma unroll
        for (int j = 0; j < 4; ++j) acc[i][j] = (f32x4){0.f, 0.f, 0.f, 0.f};
    mfma_nt(Qp + (size_t)bi * L * F + (size_t)blockIdx.y * 128 * F + (size_t)ks * kf, F,
            Kp + (size_t)bi * L * F + (size_t)blockIdx.x * 128 * F + (size_t)ks * kf, F,
            kf / 32, wave, lane, lAs, lBs, acc);
    const int wm = (wave >> 1) * 64, wn = (wave & 1) * 64;
    const int rb = (lane >> 4) * 4, cb = lane & 15;
    float* Cp = S + ((size_t)ks * Bb + bi) * L * L;
#pragma unroll
    for (int i = 0; i < 4; ++i)
#pragma unroll
        for (int reg = 0; reg < 4; ++reg) {
            int gm = blockIdx.y * 128 + wm + i * 16 + rb + reg;
#pragma unroll
            for (int j = 0; j < 4; ++j) {
                int gn = blockIdx.x * 128 + wn + j * 16 + cb;
                Cp[(size_t)gm * L + gn] = acc[i][j][reg] * scale;
            }
        }
}

// ---------------------------------------------------------------------------
// 3-head softmax (sums NSPLIT partial S buffers), combined probs -> bf16 Pb.
// ---------------------------------------------------------------------------
__device__ inline float blockMax(float v, float* sh) {
#pragma unroll
    for (int o = 32; o > 0; o >>= 1) v = fmaxf(v, __shfl_down(v, o));
    __syncthreads();
    if ((threadIdx.x & 63) == 0) sh[threadIdx.x >> 6] = v;
    __syncthreads();
    return fmaxf(fmaxf(sh[0], sh[1]), fmaxf(sh[2], sh[3]));
}
__device__ inline float blockSum(float v, float* sh) {
#pragma unroll
    for (int o = 32; o > 0; o >>= 1) v += __shfl_down(v, o);
    __syncthreads();
    if ((threadIdx.x & 63) == 0) sh[threadIdx.x >> 6] = v;
    __syncthreads();
    return sh[0] + sh[1] + sh[2] + sh[3];
}

template<int NV, int NSPLIT>
__global__ __launch_bounds__(256) void k_softmax(const float* __restrict__ S,
                                                 u16* __restrict__ Pb,
                                                 const float* __restrict__ maskf,
                                                 const float* __restrict__ smed,
                                                 const float* __restrict__ smaxA,
                                                 const float* __restrict__ sminA,
                                                 int L)
{
    __shared__ float sred[4];
    const int bi = blockIdx.y, q = blockIdx.x;
    const size_t pstr = (size_t)Bb * L * L;
    const float* row = S + (size_t)bi * L * L + (size_t)q * L;
    u16* prow = Pb + (size_t)bi * L * L + (size_t)q * L;
    const float* mk  = maskf + bi * L;
    const float* s0p = smed  + bi * L;
    const float* s1p = smaxA + bi * L;
    const float* s2p = sminA + bi * L;
    const int tid = threadIdx.x;
    float a0[NV], a1[NV], a2[NV];
    float m0 = -3.4e38f, m1 = -3.4e38f, m2 = -3.4e38f;
#pragma unroll
    for (int e = 0; e < NV; ++e) {
        int k = e * 256 + tid;
        float sv = row[k];
#pragma unroll
        for (int s2 = 1; s2 < NSPLIT; ++s2) sv += row[(size_t)s2 * pstr + k];
        bool msk = mk[k] > 0.5f;
        float v0 = msk ? -1e9f : sv * s0p[k];
        float v1 = msk ? -1e9f : sv * s1p[k];
        float v2 = msk ? -1e9f : sv * s2p[k];
        a0[e] = v0; a1[e] = v1; a2[e] = v2;
        m0 = fmaxf(m0, v0); m1 = fmaxf(m1, v1); m2 = fmaxf(m2, v2);
    }
    m0 = blockMax(m0, sred); m1 = blockMax(m1, sred); m2 = blockMax(m2, sred);
    float l0 = 0.f, l1 = 0.f, l2 = 0.f;
#pragma unroll
    for (int e = 0; e < NV; ++e) {
        a0[e] = __expf(a0[e] - m0); l0 += a0[e];
        a1[e] = __expf(a1[e] - m1); l1 += a1[e];
        a2[e] = __expf(a2[e] - m2); l2 += a2[e];
    }
    l0 = blockSum(l0, sred); l1 = blockSum(l1, sred); l2 = blockSum(l2, sred);
    float c0 = 1.f / (3.f * l0), c1 = 1.f / (3.f * l1), c2 = 1.f / (3.f * l2);
#pragma unroll
    for (int e = 0; e < NV; ++e)
        prow[e * 256 + tid] = f2bf(a0[e] * c0 + a1[e] * c1 + a2[e] * c2);
}

// ---------------------------------------------------------------------------
// Y = P @ V (LDS MFMA, split-K=4 -> 1024 blocks). Partials -> coalesced bf16
// rows Yp[ks][bi][l][f]; NHWC scatter deferred to k_unpatch.
// grid (F/128, L/128, Bb*ksplit)
// ---------------------------------------------------------------------------
__global__ __launch_bounds__(256) void k_pv_mfma(const u16* __restrict__ Pb,
                                                 const u16* __restrict__ Vt,
                                                 u16* __restrict__ Yp,
                                                 int L, int F, int ksplit)
{
    __shared__ u16 lAs[4096], lBs[4096];
    const int tid = threadIdx.x, wave = tid >> 6, lane = tid & 63;
    const int bi = blockIdx.z / ksplit, ks = blockIdx.z % ksplit;
    const int kf = L / ksplit;
    f32x4 acc[4][4];
#pragma unroll
    for (int i = 0; i < 4; ++i)
#pragma unroll
        for (int j = 0; j < 4; ++j) acc[i][j] = (f32x4){0.f, 0.f, 0.f, 0.f};
    mfma_nt(Pb + (size_t)bi * L * L + (size_t)blockIdx.y * 128 * L + (size_t)ks * kf, L,
            Vt + (size_t)bi * F * L + (size_t)blockIdx.x * 128 * L + (size_t)ks * kf, L,
            kf / 32, wave, lane, lAs, lBs, acc);
    const int wm = (wave >> 1) * 64, wn = (wave & 1) * 64;
    const int rb = (lane >> 4) * 4, cb = lane & 15;
    u16* Cp = Yp + ((size_t)(ks * Bb + bi) * L) * F;
#pragma unroll
    for (int i = 0; i < 4; ++i)
#pragma unroll
        for (int reg = 0; reg < 4; ++reg) {
            int gm = blockIdx.y * 128 + wm + i * 16 + rb + reg;
#pragma unroll
            for (int j = 0; j < 4; ++j) {
                int gn = blockIdx.x * 128 + wn + j * 16 + cb;
                Cp[(size_t)gm * F + gn] = f2bf(acc[i][j][reg]);
            }
        }
}

// ---------------------------------------------------------------------------
// Sum NSPLIT Yp partials + scatter to catbT[pix][cin].
// ---------------------------------------------------------------------------
template<int NSPLIT>
__global__ void k_unpatch(const u16* __restrict__ Yp, u16* __restrict__ catbT,
                          int ps, int outn, int L, int F, int cbase)
{
    size_t idx = (size_t)blockIdx.x * 256 + threadIdx.x;
    size_t total = (size_t)Bb * L * F / 4;
    if (idx >= total) return;
    const size_t pstr = (size_t)Bb * L * F;
    int f0 = (int)((idx * 4) % F);
    size_t t2 = (idx * 4) / F;
    int l = (int)(t2 % L);
    int bi = (int)(t2 / L);
    size_t off = ((size_t)bi * L + l) * F + f0;
    float s[4] = {0.f, 0.f, 0.f, 0.f};
#pragma unroll
    for (int sp = 0; sp < NSPLIT; ++sp) {
        uint2 u = *(const uint2*)&Yp[(size_t)sp * pstr + off];
        s[0] += bf2f((u16)(u.x & 0xffffu));
        s[1] += bf2f((u16)(u.x >> 16));
        s[2] += bf2f((u16)(u.y & 0xffffu));
        s[3] += bf2f((u16)(u.y >> 16));
    }
    int hw = ps * ps;
    int c = cbase + f0 / hw, r0 = f0 % hw;
    int ti = l / (outn * outn); int rem = l % (outn * outn);
    int oh = rem / outn, ow = rem % outn;
    int n = bi * Tt + ti;
    int py = r0 / ps, px = r0 % ps;   // r0 4-aligned -> same row, 4 consecutive px
    size_t base = ((size_t)n * PIX + (size_t)(oh * ps + py) * 64 + ow * ps + px) * Dc + c;
#pragma unroll
    for (int e = 0; e < 4; ++e)
        catbT[base + (size_t)e * Dc] = f2bf(s[e]);
}

// ---------------------------------------------------------------------------
// Output conv 3x3 as implicit NT GEMM over catbT, TAP-SPLIT 2-way:
// blockIdx.y = split, each handles 18 of the 36 flattened (tap,kc) K-chunks.
// grid (512, 2) = 1024 blocks (4 blocks/CU). bf16 [pix][cout] partials.
// OOB lanes read a zero page (per-lane global src is legal w/ global_load_lds).
// ---------------------------------------------------------------------------
__global__ __launch_bounds__(256) void k_conv_mfma(const u16* __restrict__ catbT,
                                                   const u16* __restrict__ WoT,
                                                   const u16* __restrict__ zp,
                                                   u16* __restrict__ Cpart)
{
    __shared__ u16 lAs[4096], lBs[4096];
    const int tid = threadIdx.x, wave = tid >> 6, lane = tid & 63;
    const int pix0 = blockIdx.x * 128;
    const int sp = blockIdx.y;
    const int r = lane >> 2;
    const int kq8 = ((lane & 3) ^ ((r >> 1) & 3)) * 8;   // swizzled source seg
    int yb[2], xb[2], nn[2];
#pragma unroll
    for (int s = 0; s < 2; ++s) {
        int pg = pix0 + wave * 32 + r + s * 16;
        nn[s] = pg >> 12; yb[s] = (pg >> 6) & 63; xb[s] = pg & 63;
    }
    const u16* gb_base = WoT + (size_t)(wave * 32 + r) * 128 + kq8;
    f32x4 acc[4][4];
#pragma unroll
    for (int i = 0; i < 4; ++i)
#pragma unroll
        for (int j = 0; j < 4; ++j) acc[i][j] = (f32x4){0.f, 0.f, 0.f, 0.f};
    for (int t = sp * 18; t < sp * 18 + 18; ++t) {
        const int tap = t >> 2, kc = t & 3;
        const int dy = tap / 3 - 1, dx = tap % 3 - 1;
        const u16* ga[2];
#pragma unroll
        for (int s = 0; s < 2; ++s) {
            int y = yb[s] + dy, xx = xb[s] + dx;
            bool ok = ((unsigned)y < 64u) && ((unsigned)xx < 64u);
            ga[s] = ok ? catbT + (((size_t)(nn[s] << 12) + y * 64 + xx) << 7) + kq8 + kc * 32 : zp;
        }
        const u16* gb = gb_base + tap * 16384 + kc * 32;
        __syncthreads();
        GLOAD16(ga[0], lAs + wave * 1024);
        GLOAD16(ga[1], lAs + wave * 1024 + 512);
        GLOAD16(gb, lBs + wave * 1024);
        GLOAD16(gb + 2048, lBs + wave * 1024 + 512);
        __syncthreads();
        mfma_chunk(lAs, lBs, wave, lane, acc);
    }
    const int wm = (wave >> 1) * 64, wn = (wave & 1) * 64;
    const int rb = (lane >> 4) * 4, cb = lane & 15;
    u16* Cp = Cpart + (size_t)sp * 8388608;
#pragma unroll
    for (int i = 0; i < 4; ++i)
#pragma unroll
        for (int reg = 0; reg < 4; ++reg) {
            int gm = pix0 + wm + i * 16 + rb + reg;          // global pixel
#pragma unroll
            for (int j = 0; j < 4; ++j) {
                int gn = wn + j * 16 + cb;                   // cout
                Cp[(size_t)gm * 128 + gn] = f2bf(acc[i][j][reg]);
            }
        }
}

// ---------------------------------------------------------------------------
// Conv finalize: out = leaky(sum of 2 bf16 partials + bias), NCHW fp32.
// Wave w handles couts w*32..+32, lane = pixel -> coalesced fp32 stores.
// grid (1024): 64 pixels per block.
// ---------------------------------------------------------------------------
__global__ __launch_bounds__(256) void k_cfin(const u16* __restrict__ Cpart,
                                              const float* __restrict__ bo,
                                              float* __restrict__ outp)
{
    const int pg0 = blockIdx.x * 64;
    const int lane = threadIdx.x & 63, wv = threadIdx.x >> 6;
    const int pix = pg0 + lane;
    const int n = pix >> 12, p = pix & 4095;
    const u16* r0 = Cpart + (size_t)pix * 128 + wv * 32;
    const u16* r1 = r0 + 8388608;
#pragma unroll
    for (int c4 = 0; c4 < 8; ++c4) {
        uint2 a = *(const uint2*)(r0 + c4 * 4);
        uint2 b = *(const uint2*)(r1 + c4 * 4);
        float s[4];
        s[0] = bf2f((u16)(a.x & 0xffffu)) + bf2f((u16)(b.x & 0xffffu));
        s[1] = bf2f((u16)(a.x >> 16))     + bf2f((u16)(b.x >> 16));
        s[2] = bf2f((u16)(a.y & 0xffffu)) + bf2f((u16)(b.y & 0xffffu));
        s[3] = bf2f((u16)(a.y >> 16))     + bf2f((u16)(b.y >> 16));
#pragma unroll
        for (int e = 0; e < 4; ++e) {
            int cout = wv * 32 + c4 * 4 + e;
            float v = s[e] + bo[cout];
            v = (v >= 0.f) ? v : 0.2f * v;
            outp[((size_t)n * Dc + cout) * PIX + p] = v;
        }
    }
}

// ---------------------------------------------------------------------------
extern "C" void kernel_launch(void* const* d_in, const int* in_sizes, int n_in,
                              void* d_out, int out_size, void* d_ws, size_t ws_size,
                              hipStream_t stream)
{
    (void)in_sizes; (void)n_in; (void)out_size; (void)ws_size;
    const float* x    = (const float*)d_in[0];
    const float* mI   = (const float*)d_in[1];
    const float* dmap = (const float*)d_in[2];
    const float* wq   = (const float*)d_in[3];
    const float* bq   = (const float*)d_in[4];
    const float* wk   = (const float*)d_in[5];
    const float* bk   = (const float*)d_in[6];
    const float* wv   = (const float*)d_in[7];
    const float* bv   = (const float*)d_in[8];
    const float* wvle = (const float*)d_in[9];
    const float* bvle = (const float*)d_in[10];
    const float* wd1  = (const float*)d_in[11];
    const float* bd1  = (const float*)d_in[12];
    const float* wd2  = (const float*)d_in[13];
    const float* bd2  = (const float*)d_in[14];
    const float* wo   = (const float*)d_in[15];
    const float* bo   = (const float*)d_in[16];

    // workspace layout (~190 MB)
    char* w8 = (char*)d_ws;
    u16*   q_bf  = (u16*)(w8);                    // 16 MB each
    u16*   k_bf  = (u16*)(w8 + 0x1000000);
    u16*   v_bf  = (u16*)(w8 + 0x2000000);
    u16*   Xt    = (u16*)(w8 + 0x3000000);
    u16*   catbT = (u16*)(w8 + 0x4000000);
    u16*   Qp    = (u16*)(w8 + 0x5000000);        // 8 MB each
    u16*   Kp    = (u16*)(w8 + 0x5800000);
    u16*   Vt    = (u16*)(w8 + 0x6000000);
    float* Sb    = (float*)(w8 + 0x6800000);      // 32 MB; qkT i=1 split-32 spills into Yp (dead then)
    u16*   Yp    = (u16*)(w8 + 0x8800000);        // 32 MB pv partials (written AFTER softmax consumed Sb overflow)
    u16*   Pb    = (u16*)(w8 + 0xA800000);        // 16 MB
    u16*   Cpart = (u16*)(w8 + 0x6800000);        // conv partials: reuse Sb (dead after softmax i=1)
    // d1b (67 MB) ALIASES Qp..Yp: depth path runs strictly before the attn loop
    u16*   d1b   = (u16*)(w8 + 0x5000000);
    float* dep   = (float*)(w8 + 0xB800000);
    float* maskf = (float*)(w8 + 0xB840000);
    float* smed  = (float*)(w8 + 0xB844000);
    float* smaxA = (float*)(w8 + 0xB848000);
    float* sminA = (float*)(w8 + 0xB84C000);
    u16*   Wqkv  = (u16*)(w8 + 0xB850000);
    u16*   WoT   = (u16*)(w8 + 0xB868000);
    u16*   zp    = (u16*)(w8 + 0xB8B0000);
    float* part  = (float*)(w8 + 0xB8C0000);      // 2 MB
    float* outp  = (float*)d_out;

    hipMemcpyAsync(outp + 8388608, dmap, (size_t)16 * 65536 * sizeof(float),
                   hipMemcpyDeviceToDevice, stream);
    hipMemsetAsync(zp, 0, 256, stream);

    dim3 blk(256);
    // depth path first (d1b aliases attention scratch)
    k_d1<<<dim3(32, 16), blk, 0, stream>>>(dmap, wd1, bd1, d1b);
    k_d2p<<<dim3(4, 16, 8), blk, 0, stream>>>(d1b, wd2, part);
    k_dfin<<<dim3(256), blk, 0, stream>>>(part, bd2, dep);

    k_prep<<<dim3(768), blk, 0, stream>>>(wq, wk, wv, wo, Wqkv, WoT);
    k_xt<<<dim3(64, 16), blk, 0, stream>>>(x, Xt);
    k_qkv_mfma<<<dim3(32, 3, 16), blk, 0, stream>>>(Wqkv, Xt, bq, bk, bv, q_bf, k_bf, v_bf);
    k_vdw<<<dim3(16, 128, 16), blk, 0, stream>>>(x, wvle, bvle, v_bf);

    for (int i = 0; i < 2; ++i) {
        const int ps = (i == 0) ? 4 : 8;
        const int outn = 64 / ps;
        const int L = Tt * outn * outn;        // 2048 / 512
        const int F = 64 * ps * ps;            // 1024 / 4096
        const int cbase = i * 64;
        const float scale = 1.0f / sqrtf((float)F);
        // splits chosen so every MFMA grid is >= 1024 blocks (4 blocks/CU)
        const int ksplit  = (i == 0) ? 2 : 32; // qkT: 16*16*2*2=1024 / 4*4*2*32=1024
        const int pvsplit = 4;                 // pv:  8*16*2*4=1024 / 32*4*2*4=1024

        if (i == 0) k_stats2<4><<<dim3(Bb * L * 16 / 256), blk, 0, stream>>>(mI, dep, maskf, smed, smaxA, sminA, outn, L);
        else        k_stats2<8><<<dim3(Bb * L * 64 / 256), blk, 0, stream>>>(mI, dep, maskf, smed, smaxA, sminA, outn, L);

        const int pgrid = (int)(((size_t)Bb * L * F / 4 + 255) / 256);
        k_patch_bf<<<dim3(pgrid), blk, 0, stream>>>(q_bf, Qp, ps, outn, L, F, cbase);
        k_patch_bf<<<dim3(pgrid), blk, 0, stream>>>(k_bf, Kp, ps, outn, L, F, cbase);
        k_patchT<<<dim3(pgrid), blk, 0, stream>>>(v_bf, Vt, ps, outn, L, F, cbase);

        k_qkT_mfma<<<dim3(L / 128, L / 128, Bb * ksplit), blk, 0, stream>>>(Qp, Kp, Sb, L, F, ksplit, scale);

        if (i == 0) k_softmax<8, 2><<<dim3(L, Bb), blk, 0, stream>>>(Sb, Pb, maskf, smed, smaxA, sminA, L);
        else        k_softmax<2, 32><<<dim3(L, Bb), blk, 0, stream>>>(Sb, Pb, maskf, smed, smaxA, sminA, L);

        k_pv_mfma<<<dim3(F / 128, L / 128, Bb * pvsplit), blk, 0, stream>>>(Pb, Vt, Yp, L, F, pvsplit);
        k_unpatch<4><<<dim3(pgrid), blk, 0, stream>>>(Yp, catbT, ps, outn, L, F, cbase);
    }

    k_conv_mfma<<<dim3(512, 2), blk, 0, stream>>>(catbT, WoT, zp, Cpart);
    k_cfin<<<dim3(1024), blk, 0, stream>>>(Cpart, bo, outp);
}

// Round 8
// 464.304 us; speedup vs baseline: 1.3836x; 1.1697x over previous
//
#include <hip/hip_runtime.h>
#include <cmath>

typedef unsigned short u16;
typedef __attribute__((ext_vector_type(8))) __bf16 bf16x8;
typedef __attribute__((ext_vector_type(4))) float f32x4;

constexpr int Bb = 2, Tt = 8, Dc = 128, PIX = 4096; // b=2, c=128, 64x64 imgs

__device__ inline u16 f2bf(float f) {
    unsigned u = __builtin_bit_cast(unsigned, f);
    u += 0x7fffu + ((u >> 16) & 1u);
    return (u16)(u >> 16);
}
__device__ inline float bf2f(u16 h) {
    unsigned u = ((unsigned)h) << 16;
    return __builtin_bit_cast(float, u);
}

#define GLOAD16(gp, lp) __builtin_amdgcn_global_load_lds( \
    (const __attribute__((address_space(1))) void*)(const void*)(gp), \
    (__attribute__((address_space(3))) void*)(void*)(lp), 16, 0, 0)

// ---------------------------------------------------------------------------
// bf16 NT MFMA core (m97 pattern): C(128x128) = A(128xK)*B(128xK)^T.
// LDS [row][kseg], XOR swizzle -> 0 bank conflicts. Callers launch >=512
// blocks (r7 lesson: occupancy/TLP is what hides staging latency; manual
// register pipelines get collapsed by the compiler).
// ---------------------------------------------------------------------------
__device__ inline void mfma_chunk(const u16* lAs, const u16* lBs, int wave, int lane,
                                  f32x4 (&acc)[4][4])
{
    const int wm = (wave >> 1) * 64, wn = (wave & 1) * 64;
    const int fr = lane & 15;
    const int q4 = lane >> 4;                         // wanted global k-quarter
    const int sw = (q4 ^ ((fr >> 1) & 3)) * 8;        // swizzled storage seg
    bf16x8 av[4], bv[4];
#pragma unroll
    for (int i = 0; i < 4; ++i) av[i] = *(const bf16x8*)&lAs[(wm + i * 16 + fr) * 32 + sw];
#pragma unroll
    for (int j = 0; j < 4; ++j) bv[j] = *(const bf16x8*)&lBs[(wn + j * 16 + fr) * 32 + sw];
#pragma unroll
    for (int i = 0; i < 4; ++i)
#pragma unroll
        for (int j = 0; j < 4; ++j)
            acc[i][j] = __builtin_amdgcn_mfma_f32_16x16x32_bf16(av[i], bv[j], acc[i][j], 0, 0, 0);
}

__device__ inline void mfma_nt(const u16* A, int ldkA, const u16* B, int ldkB,
                               int kChunks, int wave, int lane,
                               u16* lAs, u16* lBs, f32x4 (&acc)[4][4])
{
    const int r = lane >> 2;                              // row within 16-group
    const int kq8 = ((lane & 3) ^ ((r >> 1) & 3)) * 8;    // swizzled source seg
    const u16* ga0 = A + (size_t)(wave * 32 + r) * ldkA + kq8;
    const u16* ga1 = ga0 + (size_t)16 * ldkA;
    const u16* gb0 = B + (size_t)(wave * 32 + r) * ldkB + kq8;
    const u16* gb1 = gb0 + (size_t)16 * ldkB;
    for (int kb = 0; kb < kChunks; ++kb) {
        __syncthreads();                       // WAR: prior chunk's ds_reads done
        GLOAD16(ga0 + kb * 32, lAs + wave * 1024);
        GLOAD16(ga1 + kb * 32, lAs + wave * 1024 + 512);
        GLOAD16(gb0 + kb * 32, lBs + wave * 1024);
        GLOAD16(gb1 + kb * 32, lBs + wave * 1024 + 512);
        __syncthreads();                       // drains vmcnt(0) before barrier
        mfma_chunk(lAs, lBs, wave, lane, acc);
    }
}

// ---------------------------------------------------------------------------
// Weight prep: Wqkv[3*128][128] bf16 stacked; WoT[tap][cout][cin] bf16.
// ---------------------------------------------------------------------------
__global__ void k_prep(const float* __restrict__ wq, const float* __restrict__ wk,
                       const float* __restrict__ wv, const float* __restrict__ wo,
                       u16* __restrict__ Wqkv, u16* __restrict__ WoT)
{
    int idx = blockIdx.x * 256 + threadIdx.x;
    if (idx < 49152) {
        const float* w = idx < 16384 ? wq : (idx < 32768 ? wk : wv);
        Wqkv[idx] = f2bf(w[idx & 16383]);
    }
    int j = idx - 49152;
    if (j >= 0 && j < 147456) {
        int tap = j / 16384, rem = j % 16384;  // rem = cout*128+cin
        WoT[j] = f2bf(wo[(size_t)rem * 9 + tap]);
    }
}

// ---------------------------------------------------------------------------
// Xt[n][pix][cin] bf16 from x[n][cin][pix] fp32 (LDS transpose, 64-pix tiles)
// ---------------------------------------------------------------------------
__global__ __launch_bounds__(256) void k_xt(const float* __restrict__ x, u16* __restrict__ Xt)
{
    __shared__ float ls[128 * 65];
    const int n = blockIdx.y, pix0 = blockIdx.x * 64;
#pragma unroll
    for (int rep = 0; rep < 32; ++rep) {
        int idx = rep * 256 + threadIdx.x;
        int cin = idx >> 6, p = idx & 63;
        ls[cin * 65 + p] = x[((size_t)n * Dc + cin) * PIX + pix0 + p];
    }
    __syncthreads();
#pragma unroll
    for (int rep = 0; rep < 32; ++rep) {
        int idx = rep * 256 + threadIdx.x;
        int p = idx >> 7, cin = idx & 127;
        Xt[((size_t)n * PIX + pix0 + p) * Dc + cin] = f2bf(ls[cin * 65 + p]);
    }
}

// ---------------------------------------------------------------------------
// Fused QKV GEMM. NEW (r8): Q and K are scattered DIRECTLY into patched
// layouts for both scales (Qp0/Qp1/Kp0/Kp1) -- the c<64 / c>=64 scale split
// is wave-uniform (wm in {0,64}). Eliminates q_bf/k_bf buffers and the 4
// k_patch_bf passes. V still goes to NCHW v_bf (needs depthwise add).
// grid (32 pixtiles, 3 mt, 16 imgs) = 1536 blocks.
// ---------------------------------------------------------------------------
__global__ __launch_bounds__(256) void k_qkv_mfma(const u16* __restrict__ Wqkv,
                                                  const u16* __restrict__ Xt,
                                                  const float* __restrict__ bq,
                                                  const float* __restrict__ bk,
                                                  const float* __restrict__ bv,
                                                  u16* __restrict__ Qp0, u16* __restrict__ Kp0,
                                                  u16* __restrict__ Qp1, u16* __restrict__ Kp1,
                                                  u16* __restrict__ v_bf)
{
    __shared__ u16 lAs[4096], lBs[4096];
    const int tid = threadIdx.x, wave = tid >> 6, lane = tid & 63;
    const int mt = blockIdx.y, n = blockIdx.z, px0 = blockIdx.x * 128;
    f32x4 acc[4][4];
#pragma unroll
    for (int i = 0; i < 4; ++i)
#pragma unroll
        for (int j = 0; j < 4; ++j) acc[i][j] = (f32x4){0.f, 0.f, 0.f, 0.f};
    mfma_nt(Wqkv + (size_t)mt * 128 * 128, 128,
            Xt + ((size_t)n * PIX + px0) * 128, 128, 4, wave, lane, lAs, lBs, acc);
    const int wm = (wave >> 1) * 64, wn = (wave & 1) * 64;
    const int rb = (lane >> 4) * 4, cb = lane & 15;
    const int bi = n >> 3, ti = n & 7;
    if (mt < 2) {
        const float* bp = (mt == 0) ? bq : bk;
        u16* d0 = (mt == 0) ? Qp0 : Kp0;
        u16* d1 = (mt == 0) ? Qp1 : Kp1;
#pragma unroll
        for (int i = 0; i < 4; ++i)
#pragma unroll
            for (int reg = 0; reg < 4; ++reg) {
                int c = wm + i * 16 + rb + reg;          // 0..127
                float bias = bp[c];
#pragma unroll
                for (int j = 0; j < 4; ++j) {
                    int pix = px0 + wn + j * 16 + cb;
                    int y = pix >> 6, x = pix & 63;
                    u16 val = f2bf(acc[i][j][reg] + bias);
                    if (c < 64) {                         // scale 0 (ps=4)
                        int l = ti * 256 + (y >> 2) * 16 + (x >> 2);
                        int f = c * 16 + (y & 3) * 4 + (x & 3);
                        d0[((size_t)bi * 2048 + l) * 1024 + f] = val;
                    } else {                              // scale 1 (ps=8)
                        int l = ti * 64 + (y >> 3) * 8 + (x >> 3);
                        int f = (c - 64) * 64 + (y & 7) * 8 + (x & 7);
                        d1[((size_t)bi * 512 + l) * 4096 + f] = val;
                    }
                }
            }
    } else {
#pragma unroll
        for (int i = 0; i < 4; ++i)
#pragma unroll
            for (int reg = 0; reg < 4; ++reg) {
                int c = wm + i * 16 + rb + reg;
                float bias = bv[c];
#pragma unroll
                for (int j = 0; j < 4; ++j) {
                    int pix = px0 + wn + j * 16 + cb;
                    v_bf[((size_t)n * Dc + c) * PIX + pix] = f2bf(acc[i][j][reg] + bias);
                }
            }
    }
}

// ---------------------------------------------------------------------------
// Depthwise 3x3 add into bf16 v_all, REWRITTEN (r8): one block per (c,n)
// image; x staged in LDS once (float4); lane = x column (stride-1 LDS,
// conflict-free); 16 rows/thread; coalesced 128B RMW rows.
// Replaces the 9-global-loads-per-pixel version (52 us, VALUBusy 20%).
// grid (128, 16).
// ---------------------------------------------------------------------------
__global__ __launch_bounds__(256) void k_vdw(const float* __restrict__ X,
                                             const float* __restrict__ wvle,
                                             const float* __restrict__ bvle,
                                             u16* __restrict__ v_bf)
{
    __shared__ float ls[4096];
    const int c = blockIdx.x, n = blockIdx.y;
    const int tid = threadIdx.x;
    const float* xp = X + ((size_t)n * Dc + c) * PIX;
#pragma unroll
    for (int r = 0; r < 4; ++r)
        *(float4*)&ls[r * 1024 + tid * 4] = *(const float4*)&xp[r * 1024 + tid * 4];
    __syncthreads();
    float w[9];
#pragma unroll
    for (int t = 0; t < 9; ++t) w[t] = wvle[c * 9 + t];   // uniform -> s_load
    const float bias = bvle[c];
    const int x = tid & 63, y0 = (tid >> 6) * 16;
    const bool xl = (x > 0), xr = (x < 63);
    u16* vp = v_bf + ((size_t)n * Dc + c) * PIX;
#pragma unroll
    for (int r = 0; r < 16; ++r) {
        int y = y0 + r;
        float s = bias;
#pragma unroll
        for (int ky = 0; ky < 3; ++ky) {
            int yy = y + ky - 1;
            if (yy < 0 || yy > 63) continue;              // wave-uniform edges
            const float* row = &ls[yy * 64];
            float m  = row[x];
            float lv = xl ? row[x - 1] : 0.f;
            float rv = xr ? row[x + 1] : 0.f;
            s += w[ky * 3 + 0] * lv + w[ky * 3 + 1] * m + w[ky * 3 + 2] * rv;
        }
        int idx = y * 64 + x;
        vp[idx] = f2bf(bf2f(vp[idx]) + s);
    }
}

// ---------------------------------------------------------------------------
// Depth path, kernel 1: d1[n][c][128][128] = relu(conv(dm, wd1, s2, p1)) bf16.
// ---------------------------------------------------------------------------
__global__ __launch_bounds__(256) void k_d1(const float* __restrict__ dm,
                                            const float* __restrict__ wd1,
                                            const float* __restrict__ bd1,
                                            u16* __restrict__ d1b)
{
    __shared__ float ls[17 * 132];
    const int n = blockIdx.y;
    const int yt = blockIdx.x >> 1, xh = blockIdx.x & 1;
    const int Y0 = yt * 8;
    const int tid = threadIdx.x;
    const float* dmp = dm + (size_t)n * 65536;
    for (int idx = tid; idx < 17 * 132; idx += 256) {
        int row = idx / 132, cl = idx % 132;
        int gr = 2 * Y0 - 1 + row;
        int gc = 128 * xh - 1 + cl;
        float v = 0.f;
        if (gr >= 0 && gr < 256 && gc >= 0 && gc < 256 && cl < 129) v = dmp[gr * 256 + gc];
        ls[idx] = v;
    }
    __syncthreads();
    const int Xl = tid & 63;
    const int Yl0 = tid >> 6;                 // rows Yl0 and Yl0+4
    float in0[9], in1[9];
#pragma unroll
    for (int jy = 0; jy < 3; ++jy)
#pragma unroll
        for (int jx = 0; jx < 3; ++jx) {
            in0[jy * 3 + jx] = ls[(2 * Yl0 + jy) * 132 + 2 * Xl + jx];
            in1[jy * 3 + jx] = ls[(2 * (Yl0 + 4) + jy) * 132 + 2 * Xl + jx];
        }
    const int X = 64 * xh + Xl;
    u16* outbase = d1b + (size_t)n * Dc * 16384 + (size_t)Y0 * 128 + X;
    for (int c = 0; c < 128; ++c) {
        const float* w1 = wd1 + c * 9;        // uniform -> s_load
        float a0 = bd1[c], a1 = a0;
#pragma unroll
        for (int t = 0; t < 9; ++t) { a0 += w1[t] * in0[t]; a1 += w1[t] * in1[t]; }
        u16* ob = outbase + (size_t)c * 16384;
        ob[(size_t)Yl0 * 128]       = f2bf(fmaxf(a0, 0.f));
        ob[(size_t)(Yl0 + 4) * 128] = f2bf(fmaxf(a1, 0.f));
    }
}

// ---------------------------------------------------------------------------
// Depth path, kernel 2: partial conv2 over 16-channel groups.
// ---------------------------------------------------------------------------
__global__ __launch_bounds__(256) void k_d2p(const u16* __restrict__ d1b,
                                             const float* __restrict__ wd2,
                                             float* __restrict__ part)
{
    __shared__ u16 ls[33 * 136];              // payload at cl 8..135, zero at cl 7
    const int yt = blockIdx.x, n = blockIdx.y, cg = blockIdx.z;
    const int tid = threadIdx.x;
    const int y0 = yt * 16;
    if (tid < 33) ls[tid * 136 + 7] = 0;
    const int x = tid & 63;
    const int yl0 = (tid >> 6) * 4;
    float acc[4] = {0.f, 0.f, 0.f, 0.f};
    for (int c = 0; c < 16; ++c) {
        const u16* src = d1b + ((size_t)n * Dc + cg * 16 + c) * 16384;
        __syncthreads();
        for (int idx = tid; idx < 33 * 16; idx += 256) {
            int row = idx >> 4, s = idx & 15;
            int gr = 2 * y0 - 1 + row;
            uint4 v = make_uint4(0, 0, 0, 0);
            if (gr >= 0 && gr < 128) v = *(const uint4*)(src + gr * 128 + s * 8);
            *(uint4*)&ls[row * 136 + 8 + s * 8] = v;
        }
        __syncthreads();
        const float* w2 = wd2 + (cg * 16 + c) * 9;   // uniform -> s_load
        float w[9];
#pragma unroll
        for (int t = 0; t < 9; ++t) w[t] = w2[t];
#pragma unroll
        for (int r = 0; r < 4; ++r) {
            int yl = yl0 + r;
#pragma unroll
            for (int ky = 0; ky < 3; ++ky) {
                const u16* rp = &ls[(2 * yl + ky) * 136 + 2 * x + 7];
                float v0 = bf2f(rp[0]);
                unsigned pr = *(const unsigned*)(rp + 1);
                float v1 = bf2f((u16)(pr & 0xffffu));
                float v2 = bf2f((u16)(pr >> 16));
                acc[r] += w[ky * 3 + 0] * v0 + w[ky * 3 + 1] * v1 + w[ky * 3 + 2] * v2;
            }
        }
    }
    float* pp = part + ((size_t)cg * 16 + n) * PIX;
#pragma unroll
    for (int r = 0; r < 4; ++r)
        pp[(y0 + yl0 + r) * 64 + x] = acc[r];
}

// Depth path, kernel 3: dep = relu(sum_cg part + bd2). grid (256)
__global__ void k_dfin(const float* __restrict__ part, const float* __restrict__ bd2,
                       float* __restrict__ dep)
{
    int idx = blockIdx.x * 256 + threadIdx.x;
    float s = bd2[0];
#pragma unroll
    for (int cg = 0; cg < 8; ++cg) s += part[(size_t)cg * 65536 + idx];
    dep[idx] = fmaxf(s, 0.f);
}

// ---------------------------------------------------------------------------
// Wave-parallel per-token stats (min/max/mask butterfly, exact median rank).
// ---------------------------------------------------------------------------
template<int PS>
__global__ __launch_bounds__(256) void k_stats2(const float* __restrict__ mI,
                                                const float* __restrict__ dep,
                                                float* __restrict__ maskf,
                                                float* __restrict__ smed,
                                                float* __restrict__ smaxA,
                                                float* __restrict__ sminA,
                                                int outn, int L)
{
    constexpr int HW = PS * PS;              // 16 or 64
    constexpr int TPB = 256 / HW;
    const int tok = blockIdx.x * TPB + threadIdx.x / HW;
    const int el  = threadIdx.x % HW;
    if (tok >= Bb * L) return;
    const int bi = tok / L, l = tok % L;
    const int ti = l / (outn * outn); const int rem = l % (outn * outn);
    const int oh = rem / outn, ow = rem % outn;
    const int n = bi * Tt + ti;
    const int py = el / PS, px = el % PS;
    const size_t off = (size_t)n * PIX + (size_t)(oh * PS + py) * 64 + ow * PS + px;
    const float mv = mI[off];
    const float dv = dep[off];
    float msum = mv, vmin = dv, vmax = dv;
#pragma unroll
    for (int o = HW / 2; o > 0; o >>= 1) {
        msum += __shfl_xor(msum, o);
        vmin = fminf(vmin, __shfl_xor(vmin, o));
        vmax = fmaxf(vmax, __shfl_xor(vmax, o));
    }
    const int gbase = (threadIdx.x & 63) & ~(HW - 1);
    int cl = 0, ce = 0;
#pragma unroll
    for (int b2 = 0; b2 < HW; ++b2) {
        float vb = __shfl(dv, gbase + b2);
        cl += (vb < dv);
        ce += (vb == dv);
    }
    constexpr int kk = (HW - 1) / 2;
    if (el == 0) {
        maskf[tok] = (msum / (float)HW > 0.5f) ? 1.f : 0.f;
        smaxA[tok] = 1.f / (1.f + __expf(-vmax));
        sminA[tok] = 1.f / (1.f + __expf(-vmin));
    }
    if (cl <= kk && kk < cl + ce)
        smed[tok] = 1.f / (1.f + __expf(-dv));
}

// V transposed patch: Vt[bi][f][l] bf16. 4 consecutive l per thread.
__global__ void k_patchT(const u16* __restrict__ v_bf, u16* __restrict__ Vt,
                         int ps, int outn, int L, int F, int cbase)
{
    size_t idx = (size_t)blockIdx.x * 256 + threadIdx.x;
    size_t total = (size_t)Bb * F * L / 4;
    if (idx >= total) return;
    int l0 = (int)((idx * 4) % L);
    size_t t2 = (idx * 4) / L;
    int f = (int)(t2 % F);
    int bi = (int)(t2 / F);
    int hw = ps * ps;
    int c = cbase + f / hw, r = f % hw;
    int py = r / ps, px = r % ps;
    int ti = l0 / (outn * outn); int rem = l0 % (outn * outn);
    int oh = rem / outn, ow0 = rem % outn;
    size_t base = ((size_t)(bi * Tt + ti) * Dc + c) * PIX + (oh * ps + py) * 64 + px;
    u16 out4[4];
#pragma unroll
    for (int e = 0; e < 4; ++e) out4[e] = v_bf[base + (size_t)(ow0 + e) * ps];
    *(uint2*)&Vt[((size_t)bi * F + f) * L + l0] = *(uint2*)out4;
}

// ---------------------------------------------------------------------------
// S = scale * Q K^T (LDS MFMA), BF16 partials (r8: halves S traffic; softmax
// sums splits in fp32). grid (L/128, L/128, Bb*ksplit).
// ---------------------------------------------------------------------------
__global__ __launch_bounds__(256) void k_qkT_mfma(const u16* __restrict__ Qp,
                                                  const u16* __restrict__ Kp,
                                                  u16* __restrict__ S,
                                                  int L, int F, int ksplit, float scale)
{
    __shared__ u16 lAs[4096], lBs[4096];
    const int tid = threadIdx.x, wave = tid >> 6, lane = tid & 63;
    const int bi = blockIdx.z / ksplit, ks = blockIdx.z % ksplit;
    const int kf = F / ksplit;
    f32x4 acc[4][4];
#pragma unroll
    for (int i = 0; i < 4; ++i)
#pragma unroll
        for (int j = 0; j < 4; ++j) acc[i][j] = (f32x4){0.f, 0.f, 0.f, 0.f};
    mfma_nt(Qp + (size_t)bi * L * F + (size_t)blockIdx.y * 128 * F + (size_t)ks * kf, F,
            Kp + (size_t)bi * L * F + (size_t)blockIdx.x * 128 * F + (size_t)ks * kf, F,
            kf / 32, wave, lane, lAs, lBs, acc);
    const int wm = (wave >> 1) * 64, wn = (wave & 1) * 64;
    const int rb = (lane >> 4) * 4, cb = lane & 15;
    u16* Cp = S + ((size_t)ks * Bb + bi) * L * L;
#pragma unroll
    for (int i = 0; i < 4; ++i)
#pragma unroll
        for (int reg = 0; reg < 4; ++reg) {
            int gm = blockIdx.y * 128 + wm + i * 16 + rb + reg;
#pragma unroll
            for (int j = 0; j < 4; ++j) {
                int gn = blockIdx.x * 128 + wn + j * 16 + cb;
                Cp[(size_t)gm * L + gn] = f2bf(acc[i][j][reg] * scale);
            }
        }
}

// ---------------------------------------------------------------------------
// 3-head softmax (sums NSPLIT bf16 partial S buffers in fp32) -> bf16 Pb.
// ---------------------------------------------------------------------------
__device__ inline float blockMax(float v, float* sh) {
#pragma unroll
    for (int o = 32; o > 0; o >>= 1) v = fmaxf(v, __shfl_down(v, o));
    __syncthreads();
    if ((threadIdx.x & 63) == 0) sh[threadIdx.x >> 6] = v;
    __syncthreads();
    return fmaxf(fmaxf(sh[0], sh[1]), fmaxf(sh[2], sh[3]));
}
__device__ inline float blockSum(float v, float* sh) {
#pragma unroll
    for (int o = 32; o > 0; o >>= 1) v += __shfl_down(v, o);
    __syncthreads();
    if ((threadIdx.x & 63) == 0) sh[threadIdx.x >> 6] = v;
    __syncthreads();
    return sh[0] + sh[1] + sh[2] + sh[3];
}

template<int NV, int NSPLIT>
__global__ __launch_bounds__(256) void k_softmax(const u16* __restrict__ S,
                                                 u16* __restrict__ Pb,
                                                 const float* __restrict__ maskf,
                                                 const float* __restrict__ smed,
                                                 const float* __restrict__ smaxA,
                                                 const float* __restrict__ sminA,
                                                 int L)
{
    __shared__ float sred[4];
    const int bi = blockIdx.y, q = blockIdx.x;
    const size_t pstr = (size_t)Bb * L * L;
    const u16* row = S + (size_t)bi * L * L + (size_t)q * L;
    u16* prow = Pb + (size_t)bi * L * L + (size_t)q * L;
    const float* mk  = maskf + bi * L;
    const float* s0p = smed  + bi * L;
    const float* s1p = smaxA + bi * L;
    const float* s2p = sminA + bi * L;
    const int tid = threadIdx.x;
    float a0[NV], a1[NV], a2[NV];
    float m0 = -3.4e38f, m1 = -3.4e38f, m2 = -3.4e38f;
#pragma unroll
    for (int e = 0; e < NV; ++e) {
        int k = e * 256 + tid;
        float sv = bf2f(row[k]);
#pragma unroll
        for (int s2 = 1; s2 < NSPLIT; ++s2) sv += bf2f(row[(size_t)s2 * pstr + k]);
        bool msk = mk[k] > 0.5f;
        float v0 = msk ? -1e9f : sv * s0p[k];
        float v1 = msk ? -1e9f : sv * s1p[k];
        float v2 = msk ? -1e9f : sv * s2p[k];
        a0[e] = v0; a1[e] = v1; a2[e] = v2;
        m0 = fmaxf(m0, v0); m1 = fmaxf(m1, v1); m2 = fmaxf(m2, v2);
    }
    m0 = blockMax(m0, sred); m1 = blockMax(m1, sred); m2 = blockMax(m2, sred);
    float l0 = 0.f, l1 = 0.f, l2 = 0.f;
#pragma unroll
    for (int e = 0; e < NV; ++e) {
        a0[e] = __expf(a0[e] - m0); l0 += a0[e];
        a1[e] = __expf(a1[e] - m1); l1 += a1[e];
        a2[e] = __expf(a2[e] - m2); l2 += a2[e];
    }
    l0 = blockSum(l0, sred); l1 = blockSum(l1, sred); l2 = blockSum(l2, sred);
    float c0 = 1.f / (3.f * l0), c1 = 1.f / (3.f * l1), c2 = 1.f / (3.f * l2);
#pragma unroll
    for (int e = 0; e < NV; ++e)
        prow[e * 256 + tid] = f2bf(a0[e] * c0 + a1[e] * c1 + a2[e] * c2);
}

// ---------------------------------------------------------------------------
// Y = P @ V (LDS MFMA, split-K=4 -> 1024 blocks). Partials -> coalesced bf16
// rows Yp[ks][bi][l][f]; NHWC scatter deferred to k_unpatch.
// ---------------------------------------------------------------------------
__global__ __launch_bounds__(256) void k_pv_mfma(const u16* __restrict__ Pb,
                                                 const u16* __restrict__ Vt,
                                                 u16* __restrict__ Yp,
                                                 int L, int F, int ksplit)
{
    __shared__ u16 lAs[4096], lBs[4096];
    const int tid = threadIdx.x, wave = tid >> 6, lane = tid & 63;
    const int bi = blockIdx.z / ksplit, ks = blockIdx.z % ksplit;
    const int kf = L / ksplit;
    f32x4 acc[4][4];
#pragma unroll
    for (int i = 0; i < 4; ++i)
#pragma unroll
        for (int j = 0; j < 4; ++j) acc[i][j] = (f32x4){0.f, 0.f, 0.f, 0.f};
    mfma_nt(Pb + (size_t)bi * L * L + (size_t)blockIdx.y * 128 * L + (size_t)ks * kf, L,
            Vt + (size_t)bi * F * L + (size_t)blockIdx.x * 128 * L + (size_t)ks * kf, L,
            kf / 32, wave, lane, lAs, lBs, acc);
    const int wm = (wave >> 1) * 64, wn = (wave & 1) * 64;
    const int rb = (lane >> 4) * 4, cb = lane & 15;
    u16* Cp = Yp + ((size_t)(ks * Bb + bi) * L) * F;
#pragma unroll
    for (int i = 0; i < 4; ++i)
#pragma unroll
        for (int reg = 0; reg < 4; ++reg) {
            int gm = blockIdx.y * 128 + wm + i * 16 + rb + reg;
#pragma unroll
            for (int j = 0; j < 4; ++j) {
                int gn = blockIdx.x * 128 + wn + j * 16 + cb;
                Cp[(size_t)gm * F + gn] = f2bf(acc[i][j][reg]);
            }
        }
}

// ---------------------------------------------------------------------------
// Sum NSPLIT Yp partials + scatter to catbT[pix][cin].
// ---------------------------------------------------------------------------
template<int NSPLIT>
__global__ void k_unpatch(const u16* __restrict__ Yp, u16* __restrict__ catbT,
                          int ps, int outn, int L, int F, int cbase)
{
    size_t idx = (size_t)blockIdx.x * 256 + threadIdx.x;
    size_t total = (size_t)Bb * L * F / 4;
    if (idx >= total) return;
    const size_t pstr = (size_t)Bb * L * F;
    int f0 = (int)((idx * 4) % F);
    size_t t2 = (idx * 4) / F;
    int l = (int)(t2 % L);
    int bi = (int)(t2 / L);
    size_t off = ((size_t)bi * L + l) * F + f0;
    float s[4] = {0.f, 0.f, 0.f, 0.f};
#pragma unroll
    for (int sp = 0; sp < NSPLIT; ++sp) {
        uint2 u = *(const uint2*)&Yp[(size_t)sp * pstr + off];
        s[0] += bf2f((u16)(u.x & 0xffffu));
        s[1] += bf2f((u16)(u.x >> 16));
        s[2] += bf2f((u16)(u.y & 0xffffu));
        s[3] += bf2f((u16)(u.y >> 16));
    }
    int hw = ps * ps;
    int c = cbase + f0 / hw, r0 = f0 % hw;
    int ti = l / (outn * outn); int rem = l % (outn * outn);
    int oh = rem / outn, ow = rem % outn;
    int n = bi * Tt + ti;
    int py = r0 / ps, px = r0 % ps;   // r0 4-aligned -> same row, 4 consecutive px
    size_t base = ((size_t)n * PIX + (size_t)(oh * ps + py) * 64 + ow * ps + px) * Dc + c;
#pragma unroll
    for (int e = 0; e < 4; ++e)
        catbT[base + (size_t)e * Dc] = f2bf(s[e]);
}

// ---------------------------------------------------------------------------
// Output conv 3x3 as implicit NT GEMM over catbT, tap-split 2-way.
// grid (512, 2) = 1024 blocks. bf16 [pix][cout] partials.
// ---------------------------------------------------------------------------
__global__ __launch_bounds__(256) void k_conv_mfma(const u16* __restrict__ catbT,
                                                   const u16* __restrict__ WoT,
                                                   const u16* __restrict__ zp,
                                                   u16* __restrict__ Cpart)
{
    __shared__ u16 lAs[4096], lBs[4096];
    const int tid = threadIdx.x, wave = tid >> 6, lane = tid & 63;
    const int pix0 = blockIdx.x * 128;
    const int sp = blockIdx.y;
    const int r = lane >> 2;
    const int kq8 = ((lane & 3) ^ ((r >> 1) & 3)) * 8;   // swizzled source seg
    int yb[2], xb[2], nn[2];
#pragma unroll
    for (int s = 0; s < 2; ++s) {
        int pg = pix0 + wave * 32 + r + s * 16;
        nn[s] = pg >> 12; yb[s] = (pg >> 6) & 63; xb[s] = pg & 63;
    }
    const u16* gb_base = WoT + (size_t)(wave * 32 + r) * 128 + kq8;
    f32x4 acc[4][4];
#pragma unroll
    for (int i = 0; i < 4; ++i)
#pragma unroll
        for (int j = 0; j < 4; ++j) acc[i][j] = (f32x4){0.f, 0.f, 0.f, 0.f};
    for (int t = sp * 18; t < sp * 18 + 18; ++t) {
        const int tap = t >> 2, kc = t & 3;
        const int dy = tap / 3 - 1, dx = tap % 3 - 1;
        const u16* ga[2];
#pragma unroll
        for (int s = 0; s < 2; ++s) {
            int y = yb[s] + dy, xx = xb[s] + dx;
            bool ok = ((unsigned)y < 64u) && ((unsigned)xx < 64u);
            ga[s] = ok ? catbT + (((size_t)(nn[s] << 12) + y * 64 + xx) << 7) + kq8 + kc * 32 : zp;
        }
        const u16* gb = gb_base + tap * 16384 + kc * 32;
        __syncthreads();
        GLOAD16(ga[0], lAs + wave * 1024);
        GLOAD16(ga[1], lAs + wave * 1024 + 512);
        GLOAD16(gb, lBs + wave * 1024);
        GLOAD16(gb + 2048, lBs + wave * 1024 + 512);
        __syncthreads();
        mfma_chunk(lAs, lBs, wave, lane, acc);
    }
    const int wm = (wave >> 1) * 64, wn = (wave & 1) * 64;
    const int rb = (lane >> 4) * 4, cb = lane & 15;
    u16* Cp = Cpart + (size_t)sp * 8388608;
#pragma unroll
    for (int i = 0; i < 4; ++i)
#pragma unroll
        for (int reg = 0; reg < 4; ++reg) {
            int gm = pix0 + wm + i * 16 + rb + reg;          // global pixel
#pragma unroll
            for (int j = 0; j < 4; ++j) {
                int gn = wn + j * 16 + cb;                   // cout
                Cp[(size_t)gm * 128 + gn] = f2bf(acc[i][j][reg]);
            }
        }
}

// ---------------------------------------------------------------------------
// Conv finalize: out = leaky(sum of 2 bf16 partials + bias), NCHW fp32.
// ---------------------------------------------------------------------------
__global__ __launch_bounds__(256) void k_cfin(const u16* __restrict__ Cpart,
                                              const float* __restrict__ bo,
                                              float* __restrict__ outp)
{
    const int pg0 = blockIdx.x * 64;
    const int lane = threadIdx.x & 63, wv = threadIdx.x >> 6;
    const int pix = pg0 + lane;
    const int n = pix >> 12, p = pix & 4095;
    const u16* r0 = Cpart + (size_t)pix * 128 + wv * 32;
    const u16* r1 = r0 + 8388608;
#pragma unroll
    for (int c4 = 0; c4 < 8; ++c4) {
        uint2 a = *(const uint2*)(r0 + c4 * 4);
        uint2 b = *(const uint2*)(r1 + c4 * 4);
        float s[4];
        s[0] = bf2f((u16)(a.x & 0xffffu)) + bf2f((u16)(b.x & 0xffffu));
        s[1] = bf2f((u16)(a.x >> 16))     + bf2f((u16)(b.x >> 16));
        s[2] = bf2f((u16)(a.y & 0xffffu)) + bf2f((u16)(b.y & 0xffffu));
        s[3] = bf2f((u16)(a.y >> 16))     + bf2f((u16)(b.y >> 16));
#pragma unroll
        for (int e = 0; e < 4; ++e) {
            int cout = wv * 32 + c4 * 4 + e;
            float v = s[e] + bo[cout];
            v = (v >= 0.f) ? v : 0.2f * v;
            outp[((size_t)n * Dc + cout) * PIX + p] = v;
        }
    }
}

// ---------------------------------------------------------------------------
extern "C" void kernel_launch(void* const* d_in, const int* in_sizes, int n_in,
                              void* d_out, int out_size, void* d_ws, size_t ws_size,
                              hipStream_t stream)
{
    (void)in_sizes; (void)n_in; (void)out_size; (void)ws_size;
    const float* x    = (const float*)d_in[0];
    const float* mI   = (const float*)d_in[1];
    const float* dmap = (const float*)d_in[2];
    const float* wq   = (const float*)d_in[3];
    const float* bq   = (const float*)d_in[4];
    const float* wk   = (const float*)d_in[5];
    const float* bk   = (const float*)d_in[6];
    const float* wv   = (const float*)d_in[7];
    const float* bv   = (const float*)d_in[8];
    const float* wvle = (const float*)d_in[9];
    const float* bvle = (const float*)d_in[10];
    const float* wd1  = (const float*)d_in[11];
    const float* bd1  = (const float*)d_in[12];
    const float* wd2  = (const float*)d_in[13];
    const float* bd2  = (const float*)d_in[14];
    const float* wo   = (const float*)d_in[15];
    const float* bo   = (const float*)d_in[16];

    // workspace layout (~180 MB)
    char* w8 = (char*)d_ws;
    u16*   v_bf  = (u16*)(w8);                    // 16 MB
    u16*   Xt    = (u16*)(w8 + 0x1000000);        // 16 MB
    u16*   catbT = (u16*)(w8 + 0x2000000);        // 16 MB
    u16*   Qp0   = (u16*)(w8 + 0x3000000);        // 8 MB each (patched Q/K, both scales)
    u16*   Kp0   = (u16*)(w8 + 0x3800000);
    u16*   Qp1   = (u16*)(w8 + 0x4000000);
    u16*   Kp1   = (u16*)(w8 + 0x4800000);
    u16*   Vt    = (u16*)(w8 + 0x5000000);        // 8 MB
    u16*   Sb    = (u16*)(w8 + 0x5800000);        // 32 MB bf16 S partials
    u16*   Pb    = (u16*)(w8 + 0x7800000);        // 16 MB
    u16*   Yp    = (u16*)(w8 + 0x8800000);        // 32 MB pv partials
    u16*   Cpart = (u16*)(w8 + 0x5800000);        // conv partials: reuse Sb (dead after softmax i=1)
    // d1b (64 MB) ALIASES Qp0..Sb: depth path runs strictly before qkv/attn
    u16*   d1b   = (u16*)(w8 + 0x3000000);
    float* dep   = (float*)(w8 + 0xA800000);
    float* maskf = (float*)(w8 + 0xA840000);
    float* smed  = (float*)(w8 + 0xA844000);
    float* smaxA = (float*)(w8 + 0xA848000);
    float* sminA = (float*)(w8 + 0xA84C000);
    u16*   Wqkv  = (u16*)(w8 + 0xA850000);
    u16*   WoT   = (u16*)(w8 + 0xA868000);
    u16*   zp    = (u16*)(w8 + 0xA8B0000);
    float* part  = (float*)(w8 + 0xA8C0000);      // 2 MB
    float* outp  = (float*)d_out;

    hipMemcpyAsync(outp + 8388608, dmap, (size_t)16 * 65536 * sizeof(float),
                   hipMemcpyDeviceToDevice, stream);
    hipMemsetAsync(zp, 0, 256, stream);

    dim3 blk(256);
    // depth path first (d1b aliases Qp/Sb scratch)
    k_d1<<<dim3(32, 16), blk, 0, stream>>>(dmap, wd1, bd1, d1b);
    k_d2p<<<dim3(4, 16, 8), blk, 0, stream>>>(d1b, wd2, part);
    k_dfin<<<dim3(256), blk, 0, stream>>>(part, bd2, dep);

    k_prep<<<dim3(768), blk, 0, stream>>>(wq, wk, wv, wo, Wqkv, WoT);
    k_xt<<<dim3(64, 16), blk, 0, stream>>>(x, Xt);
    k_qkv_mfma<<<dim3(32, 3, 16), blk, 0, stream>>>(Wqkv, Xt, bq, bk, bv,
                                                    Qp0, Kp0, Qp1, Kp1, v_bf);
    k_vdw<<<dim3(128, 16), blk, 0, stream>>>(x, wvle, bvle, v_bf);

    for (int i = 0; i < 2; ++i) {
        const int ps = (i == 0) ? 4 : 8;
        const int outn = 64 / ps;
        const int L = Tt * outn * outn;        // 2048 / 512
        const int F = 64 * ps * ps;            // 1024 / 4096
        const int cbase = i * 64;
        const float scale = 1.0f / sqrtf((float)F);
        const int ksplit  = (i == 0) ? 2 : 16; // qkT grids: 1024 / 512 blocks
        const int pvsplit = 4;                 // pv grids: 1024 / 1024 blocks
        const u16* Qp = (i == 0) ? Qp0 : Qp1;
        const u16* Kp = (i == 0) ? Kp0 : Kp1;

        if (i == 0) k_stats2<4><<<dim3(Bb * L * 16 / 256), blk, 0, stream>>>(mI, dep, maskf, smed, smaxA, sminA, outn, L);
        else        k_stats2<8><<<dim3(Bb * L * 64 / 256), blk, 0, stream>>>(mI, dep, maskf, smed, smaxA, sminA, outn, L);

        const int pgrid = (int)(((size_t)Bb * L * F / 4 + 255) / 256);
        k_patchT<<<dim3(pgrid), blk, 0, stream>>>(v_bf, Vt, ps, outn, L, F, cbase);

        k_qkT_mfma<<<dim3(L / 128, L / 128, Bb * ksplit), blk, 0, stream>>>(Qp, Kp, Sb, L, F, ksplit, scale);

        if (i == 0) k_softmax<8, 2><<<dim3(L, Bb), blk, 0, stream>>>(Sb, Pb, maskf, smed, smaxA, sminA, L);
        else        k_softmax<2, 16><<<dim3(L, Bb), blk, 0, stream>>>(Sb, Pb, maskf, smed, smaxA, sminA, L);

        k_pv_mfma<<<dim3(F / 128, L / 128, Bb * pvsplit), blk, 0, stream>>>(Pb, Vt, Yp, L, F, pvsplit);
        k_unpatch<4><<<dim3(pgrid), blk, 0, stream>>>(Yp, catbT, ps, outn, L, F, cbase);
    }

    k_conv_mfma<<<dim3(512, 2), blk, 0, stream>>>(catbT, WoT, zp, Cpart);
    k_cfin<<<dim3(1024), blk, 0, stream>>>(Cpart, bo, outp);
}